// Round 3
// baseline (23355.489 us; speedup 1.0000x reference)
//
#include <hip/hip_runtime.h>
#include <hip/hip_bf16.h>

constexpr int cV = 128, cD = 1024, cH = 1024, cB = 64, cT = 512;
constexpr int c4H = 4096;
constexpr int NBLK = 256;
constexpr int FSTR = 32;          // flag stride in ints (128 B per flag)
// h matrices [64][1024] are stored slice-wise: [128][64][8] (slice s = cols 8s..8s+7)
// addr(b, col) = (col>>3)*512 + b*8 + (col&7); each block owns one 1 KB slice region.

typedef __attribute__((ext_vector_type(8))) short bf16x8;
typedef __attribute__((ext_vector_type(4))) float f32x4;

__device__ __forceinline__ short f2b(float f) {
  __hip_bfloat16 h = __float2bfloat16(f);
  return __builtin_bit_cast(short, h);
}
__device__ __forceinline__ float sigf(float x) { return 1.0f / (1.0f + __expf(-x)); }

// ---------------- f32 -> bf16 flat converter (8 elems / thread) ----------------
__global__ void cvt_bf16_kernel(const float* __restrict__ src, short* __restrict__ dst, int n8) {
  int q = blockIdx.x * blockDim.x + threadIdx.x;
  if (q >= n8) return;
  const float4* s = (const float4*)src + (size_t)q * 2;
  float4 a = s[0], b = s[1];
  union { short s8[8]; int4 v; } u;
  u.s8[0] = f2b(a.x); u.s8[1] = f2b(a.y); u.s8[2] = f2b(a.z); u.s8[3] = f2b(a.w);
  u.s8[4] = f2b(b.x); u.s8[5] = f2b(b.y); u.s8[6] = f2b(b.z); u.s8[7] = f2b(b.w);
  *(int4*)(dst + (size_t)q * 8) = u.v;
}

// ---------------- embedding gather -> xe[t][slice][b][8] bf16 (coalesced writes) ----------------
__global__ void gather_kernel(const int* __restrict__ x, const float* __restrict__ embed,
                              short* __restrict__ xe) {
  int q = blockIdx.x * blockDim.x + threadIdx.x;  // total T*128*64
  int b = q & 63;
  int rest = q >> 6;
  int d8 = rest & 127;        // slice index
  int t = rest >> 7;
  int vix = x[b * cT + t];
  const float4* s = (const float4*)(embed + (size_t)vix * cD + d8 * 8);
  float4 a = s[0], bb = s[1];
  union { short s8[8]; int4 v; } u;
  u.s8[0] = f2b(a.x); u.s8[1] = f2b(a.y); u.s8[2] = f2b(a.z); u.s8[3] = f2b(a.w);
  u.s8[4] = f2b(bb.x); u.s8[5] = f2b(bb.y); u.s8[6] = f2b(bb.z); u.s8[7] = f2b(bb.w);
  *(int4*)(xe + (size_t)t * 65536 + d8 * 512 + b * 8) = u.v;
}

// ---------------- persistent weight-stationary recurrent kernel ----------------
struct RParams {
  const float* Wx;        // [L][4096][1024] f32
  const float* Wh;        // [L][4096][1024] f32
  const float* bias;      // [L][4096]
  const short* xe;        // [T][128][64][8] bf16 (slice layout)
  short* h0buf;           // [2][128][64][8] bf16
  short* outs;            // [T][128][64][8] bf16
  const short* zpage;     // [128][64][8] bf16 zeros
  int* flags;             // [256 * FSTR]
};

__launch_bounds__(256, 1)
__global__ void lstm_recurrent(RParams P) {
  __shared__ float pLDS[4][32][36];   // per-wave partial C [32 batch x 32 gate-cols]
  __shared__ float cLDS[cB * 8];      // persistent cell state (this block's 8 h-cols)
  __shared__ float bLDS[32];

  const int tid = threadIdx.x;
  const int lane = tid & 63, wv = tid >> 6;
  const int l15 = lane & 15, lhi = lane >> 4;
  const int mh = wv >> 1;             // batch half
  const int kh = wv & 1;              // 0: Wx/x-input, 1: Wh/h-input
  const int blk = blockIdx.x;
  const int layer = blk >> 7;
  const int slice = blk & 127;
  const int hc0 = slice * 8;

  // ---- one-time: wave's 32x1024 weight slice -> registers as B-fragments ----
  bf16x8 w[2][32];
  {
    const float* Wsrc = (kh ? P.Wh : P.Wx) + (size_t)layer * c4H * cD;
    #pragma unroll
    for (int ni = 0; ni < 2; ++ni) {
      int r = ni * 16 + l15;          // output col within the 32 gate-cols
      const float* base = Wsrc + (size_t)((r >> 3) * cH + hc0 + (r & 7)) * cD + lhi * 8;
      #pragma unroll
      for (int kt = 0; kt < 32; ++kt) {
        float4 a = *(const float4*)(base + kt * 32);
        float4 b = *(const float4*)(base + kt * 32 + 4);
        union { short s8[8]; bf16x8 v; } u;
        u.s8[0] = f2b(a.x); u.s8[1] = f2b(a.y); u.s8[2] = f2b(a.z); u.s8[3] = f2b(a.w);
        u.s8[4] = f2b(b.x); u.s8[5] = f2b(b.y); u.s8[6] = f2b(b.z); u.s8[7] = f2b(b.w);
        w[ni][kt] = u.v;
      }
    }
  }
  if (tid < 32)
    bLDS[tid] = P.bias[layer * c4H + (tid >> 3) * cH + hc0 + (tid & 7)];
  for (int q = tid; q < cB * 8; q += 256) cLDS[q] = 0.0f;
  __syncthreads();

  for (int p = 0; p <= cT; ++p) {
    const short *Ax, *Ah;
    short* hout;
    bool active;
    if (layer == 0) {
      active = (p < cT);
      Ax = P.xe + (size_t)p * 65536;
      Ah = P.h0buf + (size_t)((p + 1) & 1) * 65536;        // h0(p-1)
      hout = P.h0buf + (size_t)(p & 1) * 65536;            // h0(p)
    } else {
      int t = p - 1;
      active = (t >= 0);
      int tt = t < 0 ? 0 : t;
      Ax = P.h0buf + (size_t)((p + 1) & 1) * 65536;        // h0(t)
      Ah = (t <= 0) ? P.zpage : (P.outs + (size_t)(tt - 1) * 65536);  // h1(t-1)
      hout = P.outs + (size_t)tt * 65536;
    }

    if (active) {
      const short* Abase = kh ? Ah : Ax;
      // A[row][k], slice layout: addr = (k>>3)*512 + row*8; k = kt*32 + lhi*8
      const short* arow0 = Abase + lhi * 512 + (mh * 32 + l15) * 8;
      f32x4 acc[2][2] = {};
      #pragma unroll
      for (int kt = 0; kt < 32; ++kt) {
        bf16x8 a0 = *(const bf16x8*)(arow0 + kt * 2048);
        bf16x8 a1 = *(const bf16x8*)(arow0 + kt * 2048 + 128);   // row + 16
        acc[0][0] = __builtin_amdgcn_mfma_f32_16x16x32_bf16(a0, w[0][kt], acc[0][0], 0, 0, 0);
        acc[0][1] = __builtin_amdgcn_mfma_f32_16x16x32_bf16(a0, w[1][kt], acc[0][1], 0, 0, 0);
        acc[1][0] = __builtin_amdgcn_mfma_f32_16x16x32_bf16(a1, w[0][kt], acc[1][0], 0, 0, 0);
        acc[1][1] = __builtin_amdgcn_mfma_f32_16x16x32_bf16(a1, w[1][kt], acc[1][1], 0, 0, 0);
      }
      #pragma unroll
      for (int mi = 0; mi < 2; ++mi)
        #pragma unroll
        for (int ni = 0; ni < 2; ++ni)
          #pragma unroll
          for (int v = 0; v < 4; ++v)
            pLDS[wv][mi * 16 + lhi * 4 + v][ni * 16 + l15] = acc[mi][ni][v];
      __syncthreads();
      // fused Wx+Wh reduction + LSTM pointwise; write block-private 1 KB slice
      short* houtS = hout + slice * 512;
      for (int e = tid; e < 512; e += 256) {
        int b = e >> 3, hc = e & 7;
        int mq = (b >> 5) << 1;
        int mr = b & 31;
        float iv = pLDS[mq][mr][hc]      + pLDS[mq + 1][mr][hc]      + bLDS[hc];
        float fv = pLDS[mq][mr][8 + hc]  + pLDS[mq + 1][mr][8 + hc]  + bLDS[8 + hc];
        float gv = pLDS[mq][mr][16 + hc] + pLDS[mq + 1][mr][16 + hc] + bLDS[16 + hc];
        float ov = pLDS[mq][mr][24 + hc] + pLDS[mq + 1][mr][24 + hc] + bLDS[24 + hc];
        float cold = cLDS[e];
        float cn = sigf(fv) * cold + sigf(iv) * tanhf(gv);
        float hn = sigf(ov) * tanhf(cn);
        cLDS[e] = cn;
        houtS[e] = f2b(hn);
      }
    }

    // ---- grid barrier: per-block padded counters (RMW), all-thread coalesced poll ----
    __syncthreads();
    if (tid == 0) {
      __threadfence();
      __hip_atomic_fetch_add(&P.flags[blk * FSTR], 1, __ATOMIC_RELEASE, __HIP_MEMORY_SCOPE_AGENT);
    }
    while (__hip_atomic_load(&P.flags[tid * FSTR], __ATOMIC_ACQUIRE, __HIP_MEMORY_SCOPE_AGENT) <= p)
      __builtin_amdgcn_s_sleep(1);
    __syncthreads();
  }
}

// ---------------- output projection (outs is slice-layout) ----------------
__launch_bounds__(256, 1)
__global__ void proj_kernel(const short* __restrict__ outs, const short* __restrict__ Woutb,
                            const float* __restrict__ bout, float* __restrict__ logits) {
  const int tid = threadIdx.x, lane = tid & 63, wv = tid >> 6;
  const int l15 = lane & 15, lhi = lane >> 4;
  const int t = blockIdx.x;
  const int row = wv * 16 + l15;
  const short* Abase = outs + (size_t)t * 65536;
  f32x4 acc[8] = {};
  for (int k = 0; k < 1024; k += 32) {
    bf16x8 af = *(const bf16x8*)(Abase + ((k >> 3) + lhi) * 512 + row * 8);
    #pragma unroll
    for (int nn = 0; nn < 8; ++nn) {
      bf16x8 bf = *(const bf16x8*)(Woutb + (size_t)(nn * 16 + l15) * 1024 + k + lhi * 8);
      acc[nn] = __builtin_amdgcn_mfma_f32_16x16x32_bf16(af, bf, acc[nn], 0, 0, 0);
    }
  }
  #pragma unroll
  for (int nn = 0; nn < 8; ++nn) {
    #pragma unroll
    for (int v = 0; v < 4; ++v) {
      int b = wv * 16 + lhi * 4 + v;
      int col = nn * 16 + l15;
      logits[(size_t)b * (cT * cV) + (size_t)t * cV + col] = acc[nn][v] + bout[col];
    }
  }
}

// ---------------- launch ----------------
extern "C" void kernel_launch(void* const* d_in, const int* in_sizes, int n_in,
                              void* d_out, int out_size, void* d_ws, size_t ws_size,
                              hipStream_t stream) {
  const int* x = (const int*)d_in[0];
  const float* embed = (const float*)d_in[1];
  const float* Wx = (const float*)d_in[2];
  const float* Wh = (const float*)d_in[3];
  const float* bias = (const float*)d_in[4];
  const float* Wout = (const float*)d_in[5];
  const float* bout = (const float*)d_in[6];
  float* logits = (float*)d_out;

  char* ws = (char*)d_ws;
  size_t off = 0;
  auto alloc = [&](size_t bytes) {
    char* p = ws + off;
    off += (bytes + 255) & ~(size_t)255;
    return p;
  };
  short* Woutb = (short*)alloc((size_t)cV * cH * 2);
  short* xe    = (short*)alloc((size_t)cT * cB * cD * 2);
  short* outs  = (short*)alloc((size_t)cT * cB * cH * 2);
  char* state0 = ws + off;
  short* h0buf = (short*)alloc((size_t)2 * cB * cH * 2);
  short* zpage = (short*)alloc((size_t)cB * cH * 2);
  int* flags   = (int*)alloc((size_t)NBLK * FSTR * sizeof(int));
  size_t state_bytes = (size_t)((ws + off) - state0);

  hipMemsetAsync(state0, 0, state_bytes, stream);

  int n8wo = cV * cH / 8;
  cvt_bf16_kernel<<<(n8wo + 255) / 256, 256, 0, stream>>>(Wout, Woutb, n8wo);

  int nseg = cT * cB * (cD / 8);
  gather_kernel<<<nseg / 256, 256, 0, stream>>>(x, embed, xe);

  RParams P{Wx, Wh, bias, xe, h0buf, outs, zpage, flags};
  lstm_recurrent<<<dim3(NBLK), dim3(256), 0, stream>>>(P);

  proj_kernel<<<cT, 256, 0, stream>>>(outs, Woutb, bout, logits);
}

// Round 4
// 18155.812 us; speedup vs baseline: 1.2864x; 1.2864x over previous
//
#include <hip/hip_runtime.h>
#include <hip/hip_bf16.h>

constexpr int cV = 128, cD = 1024, cH = 1024, cB = 64, cT = 512;
constexpr int c4H = 4096;
constexpr int NBLK = 256;
constexpr int FSTR = 32;          // flag stride in ints (128 B per slot)
// h matrices [64][1024] are stored slice-wise: [128][64][8] (slice s = cols 8s..8s+7)
// addr(b, col) = (col>>3)*512 + b*8 + (col&7); each block owns one 1 KB slice region.

typedef __attribute__((ext_vector_type(8))) short bf16x8;
typedef __attribute__((ext_vector_type(4))) float f32x4;

__device__ __forceinline__ short f2b(float f) {
  __hip_bfloat16 h = __float2bfloat16(f);
  return __builtin_bit_cast(short, h);
}
__device__ __forceinline__ float sigf(float x) { return 1.0f / (1.0f + __expf(-x)); }

// ---------------- f32 -> bf16 flat converter (8 elems / thread) ----------------
__global__ void cvt_bf16_kernel(const float* __restrict__ src, short* __restrict__ dst, int n8) {
  int q = blockIdx.x * blockDim.x + threadIdx.x;
  if (q >= n8) return;
  const float4* s = (const float4*)src + (size_t)q * 2;
  float4 a = s[0], b = s[1];
  union { short s8[8]; int4 v; } u;
  u.s8[0] = f2b(a.x); u.s8[1] = f2b(a.y); u.s8[2] = f2b(a.z); u.s8[3] = f2b(a.w);
  u.s8[4] = f2b(b.x); u.s8[5] = f2b(b.y); u.s8[6] = f2b(b.z); u.s8[7] = f2b(b.w);
  *(int4*)(dst + (size_t)q * 8) = u.v;
}

// ---------------- embedding gather -> xe[t][slice][b][8] bf16 (coalesced writes) ----------------
__global__ void gather_kernel(const int* __restrict__ x, const float* __restrict__ embed,
                              short* __restrict__ xe) {
  int q = blockIdx.x * blockDim.x + threadIdx.x;  // total T*128*64
  int b = q & 63;
  int rest = q >> 6;
  int d8 = rest & 127;        // slice index
  int t = rest >> 7;
  int vix = x[b * cT + t];
  const float4* s = (const float4*)(embed + (size_t)vix * cD + d8 * 8);
  float4 a = s[0], bb = s[1];
  union { short s8[8]; int4 v; } u;
  u.s8[0] = f2b(a.x); u.s8[1] = f2b(a.y); u.s8[2] = f2b(a.z); u.s8[3] = f2b(a.w);
  u.s8[4] = f2b(bb.x); u.s8[5] = f2b(bb.y); u.s8[6] = f2b(bb.z); u.s8[7] = f2b(bb.w);
  *(int4*)(xe + (size_t)t * 65536 + d8 * 512 + b * 8) = u.v;
}

// ---------------- persistent weight-stationary recurrent kernel ----------------
struct RParams {
  const float* Wx;        // [L][4096][1024] f32
  const float* Wh;        // [L][4096][1024] f32
  const float* bias;      // [L][4096]
  const short* xe;        // [T][128][64][8] bf16 (slice layout)
  short* h0buf;           // [2][128][64][8] bf16
  short* outs;            // [T][128][64][8] bf16
  const short* zpage;     // [128][64][8] bf16 zeros
  int* flags;             // [>=10 * FSTR] ints: [g*FSTR] g=0..7 group counters,
                          //   [8*FSTR] root counter, [9*FSTR] epoch broadcast
};

__launch_bounds__(256, 1)
__global__ void lstm_recurrent(RParams P) {
  __shared__ float pLDS[4][32][36];   // per-wave partial C [32 batch x 32 gate-cols]
  __shared__ float cLDS[cB * 8];      // persistent cell state (this block's 8 h-cols)
  __shared__ float bLDS[32];

  const int tid = threadIdx.x;
  const int lane = tid & 63, wv = tid >> 6;
  const int l15 = lane & 15, lhi = lane >> 4;
  const int mh = wv >> 1;             // batch half
  const int kh = wv & 1;              // 0: Wx/x-input, 1: Wh/h-input
  const int blk = blockIdx.x;
  const int layer = blk >> 7;
  const int slice = blk & 127;
  const int hc0 = slice * 8;

  // ---- one-time: wave's 32x1024 weight slice -> registers as B-fragments ----
  bf16x8 w[2][32];
  {
    const float* Wsrc = (kh ? P.Wh : P.Wx) + (size_t)layer * c4H * cD;
    #pragma unroll
    for (int ni = 0; ni < 2; ++ni) {
      int r = ni * 16 + l15;          // output col within the 32 gate-cols
      const float* base = Wsrc + (size_t)((r >> 3) * cH + hc0 + (r & 7)) * cD + lhi * 8;
      #pragma unroll
      for (int kt = 0; kt < 32; ++kt) {
        float4 a = *(const float4*)(base + kt * 32);
        float4 b = *(const float4*)(base + kt * 32 + 4);
        union { short s8[8]; bf16x8 v; } u;
        u.s8[0] = f2b(a.x); u.s8[1] = f2b(a.y); u.s8[2] = f2b(a.z); u.s8[3] = f2b(a.w);
        u.s8[4] = f2b(b.x); u.s8[5] = f2b(b.y); u.s8[6] = f2b(b.z); u.s8[7] = f2b(b.w);
        w[ni][kt] = u.v;
      }
    }
  }
  if (tid < 32)
    bLDS[tid] = P.bias[layer * c4H + (tid >> 3) * cH + hc0 + (tid & 7)];
  for (int q = tid; q < cB * 8; q += 256) cLDS[q] = 0.0f;
  __syncthreads();

  for (int p = 0; p <= cT; ++p) {
    const short *Ax, *Ah;
    short* hout;
    bool active;
    if (layer == 0) {
      active = (p < cT);
      Ax = P.xe + (size_t)p * 65536;
      Ah = P.h0buf + (size_t)((p + 1) & 1) * 65536;        // h0(p-1)
      hout = P.h0buf + (size_t)(p & 1) * 65536;            // h0(p)
    } else {
      int t = p - 1;
      active = (t >= 0);
      int tt = t < 0 ? 0 : t;
      Ax = P.h0buf + (size_t)((p + 1) & 1) * 65536;        // h0(t)
      Ah = (t <= 0) ? P.zpage : (P.outs + (size_t)(tt - 1) * 65536);  // h1(t-1)
      hout = P.outs + (size_t)tt * 65536;
    }

    if (active) {
      const short* Abase = kh ? Ah : Ax;
      // A[row][k], slice layout: addr = (k>>3)*512 + row*8; k = kt*32 + lhi*8
      const short* arow0 = Abase + lhi * 512 + (mh * 32 + l15) * 8;
      f32x4 acc[2][2] = {};
      #pragma unroll
      for (int kt = 0; kt < 32; ++kt) {
        bf16x8 a0 = *(const bf16x8*)(arow0 + kt * 2048);
        bf16x8 a1 = *(const bf16x8*)(arow0 + kt * 2048 + 128);   // row + 16
        acc[0][0] = __builtin_amdgcn_mfma_f32_16x16x32_bf16(a0, w[0][kt], acc[0][0], 0, 0, 0);
        acc[0][1] = __builtin_amdgcn_mfma_f32_16x16x32_bf16(a0, w[1][kt], acc[0][1], 0, 0, 0);
        acc[1][0] = __builtin_amdgcn_mfma_f32_16x16x32_bf16(a1, w[0][kt], acc[1][0], 0, 0, 0);
        acc[1][1] = __builtin_amdgcn_mfma_f32_16x16x32_bf16(a1, w[1][kt], acc[1][1], 0, 0, 0);
      }
      #pragma unroll
      for (int mi = 0; mi < 2; ++mi)
        #pragma unroll
        for (int ni = 0; ni < 2; ++ni)
          #pragma unroll
          for (int v = 0; v < 4; ++v)
            pLDS[wv][mi * 16 + lhi * 4 + v][ni * 16 + l15] = acc[mi][ni][v];
      __syncthreads();
      // fused Wx+Wh reduction + LSTM pointwise; write block-private 1 KB slice
      short* houtS = hout + slice * 512;
      for (int e = tid; e < 512; e += 256) {
        int b = e >> 3, hc = e & 7;
        int mq = (b >> 5) << 1;
        int mr = b & 31;
        float iv = pLDS[mq][mr][hc]      + pLDS[mq + 1][mr][hc]      + bLDS[hc];
        float fv = pLDS[mq][mr][8 + hc]  + pLDS[mq + 1][mr][8 + hc]  + bLDS[8 + hc];
        float gv = pLDS[mq][mr][16 + hc] + pLDS[mq + 1][mr][16 + hc] + bLDS[16 + hc];
        float ov = pLDS[mq][mr][24 + hc] + pLDS[mq + 1][mr][24 + hc] + bLDS[24 + hc];
        float cold = cLDS[e];
        float cn = sigf(fv) * cold + sigf(iv) * tanhf(gv);
        float hn = sigf(ov) * tanhf(cn);
        cLDS[e] = cn;
        houtS[e] = f2b(hn);
      }
    }

    // ---- 2-level hierarchical grid barrier (monotonic counters, single epoch line) ----
    __syncthreads();
    if (tid == 0) {
      __threadfence();  // release this block's global writes (agent scope)
      int old = __hip_atomic_fetch_add(&P.flags[(blk & 7) * FSTR], 1,
                                       __ATOMIC_ACQ_REL, __HIP_MEMORY_SCOPE_AGENT);
      if (old == 32 * (p + 1) - 1) {  // last arriver of this group for phase p
        int rold = __hip_atomic_fetch_add(&P.flags[8 * FSTR], 1,
                                          __ATOMIC_ACQ_REL, __HIP_MEMORY_SCOPE_AGENT);
        if (rold == 8 * (p + 1) - 1)  // last group overall for phase p
          __hip_atomic_store(&P.flags[9 * FSTR], p + 1,
                             __ATOMIC_RELEASE, __HIP_MEMORY_SCOPE_AGENT);
      }
      while (__hip_atomic_load(&P.flags[9 * FSTR],
                               __ATOMIC_ACQUIRE, __HIP_MEMORY_SCOPE_AGENT) <= p)
        __builtin_amdgcn_s_sleep(1);
    }
    __syncthreads();
  }
}

// ---------------- output projection (outs is slice-layout) ----------------
__launch_bounds__(256, 1)
__global__ void proj_kernel(const short* __restrict__ outs, const short* __restrict__ Woutb,
                            const float* __restrict__ bout, float* __restrict__ logits) {
  const int tid = threadIdx.x, lane = tid & 63, wv = tid >> 6;
  const int l15 = lane & 15, lhi = lane >> 4;
  const int t = blockIdx.x;
  const int row = wv * 16 + l15;
  const short* Abase = outs + (size_t)t * 65536;
  f32x4 acc[8] = {};
  for (int k = 0; k < 1024; k += 32) {
    bf16x8 af = *(const bf16x8*)(Abase + ((k >> 3) + lhi) * 512 + row * 8);
    #pragma unroll
    for (int nn = 0; nn < 8; ++nn) {
      bf16x8 bf = *(const bf16x8*)(Woutb + (size_t)(nn * 16 + l15) * 1024 + k + lhi * 8);
      acc[nn] = __builtin_amdgcn_mfma_f32_16x16x32_bf16(af, bf, acc[nn], 0, 0, 0);
    }
  }
  #pragma unroll
  for (int nn = 0; nn < 8; ++nn) {
    #pragma unroll
    for (int v = 0; v < 4; ++v) {
      int b = wv * 16 + lhi * 4 + v;
      int col = nn * 16 + l15;
      logits[(size_t)b * (cT * cV) + (size_t)t * cV + col] = acc[nn][v] + bout[col];
    }
  }
}

// ---------------- launch ----------------
extern "C" void kernel_launch(void* const* d_in, const int* in_sizes, int n_in,
                              void* d_out, int out_size, void* d_ws, size_t ws_size,
                              hipStream_t stream) {
  const int* x = (const int*)d_in[0];
  const float* embed = (const float*)d_in[1];
  const float* Wx = (const float*)d_in[2];
  const float* Wh = (const float*)d_in[3];
  const float* bias = (const float*)d_in[4];
  const float* Wout = (const float*)d_in[5];
  const float* bout = (const float*)d_in[6];
  float* logits = (float*)d_out;

  char* ws = (char*)d_ws;
  size_t off = 0;
  auto alloc = [&](size_t bytes) {
    char* p = ws + off;
    off += (bytes + 255) & ~(size_t)255;
    return p;
  };
  short* Woutb = (short*)alloc((size_t)cV * cH * 2);
  short* xe    = (short*)alloc((size_t)cT * cB * cD * 2);
  short* outs  = (short*)alloc((size_t)cT * cB * cH * 2);
  char* state0 = ws + off;
  short* h0buf = (short*)alloc((size_t)2 * cB * cH * 2);
  short* zpage = (short*)alloc((size_t)cB * cH * 2);
  int* flags   = (int*)alloc((size_t)16 * FSTR * sizeof(int));
  size_t state_bytes = (size_t)((ws + off) - state0);

  hipMemsetAsync(state0, 0, state_bytes, stream);

  int n8wo = cV * cH / 8;
  cvt_bf16_kernel<<<(n8wo + 255) / 256, 256, 0, stream>>>(Wout, Woutb, n8wo);

  int nseg = cT * cB * (cD / 8);
  gather_kernel<<<nseg / 256, 256, 0, stream>>>(x, embed, xe);

  RParams P{Wx, Wh, bias, xe, h0buf, outs, zpage, flags};
  lstm_recurrent<<<dim3(NBLK), dim3(256), 0, stream>>>(P);

  proj_kernel<<<cT, 256, 0, stream>>>(outs, Woutb, bout, logits);
}

// Round 5
// 9806.640 us; speedup vs baseline: 2.3816x; 1.8514x over previous
//
#include <hip/hip_runtime.h>
#include <hip/hip_bf16.h>

constexpr int cV = 128, cD = 1024, cH = 1024, cB = 64, cT = 512;
constexpr int c4H = 4096;
constexpr int NBLK = 256;
constexpr int FSTR = 32;          // flag stride in ints (128 B per slot)
// h pages [64][1024] stored slice-wise: [128][64][8]; addr(b,col)=(col>>3)*512+b*8+(col&7)
// page size = 65536 shorts (128 KB). Each block owns one 512-short slice region.

typedef __attribute__((ext_vector_type(8))) short bf16x8;
typedef __attribute__((ext_vector_type(4))) float f32x4;

__device__ __forceinline__ short f2b(float f) {
  __hip_bfloat16 h = __float2bfloat16(f);
  return __builtin_bit_cast(short, h);
}
__device__ __forceinline__ float sigf(float x) { return 1.0f / (1.0f + __expf(-x)); }

// ---------------- f32 -> bf16 flat converter (8 elems / thread) ----------------
__global__ void cvt_bf16_kernel(const float* __restrict__ src, short* __restrict__ dst, int n8) {
  int q = blockIdx.x * blockDim.x + threadIdx.x;
  if (q >= n8) return;
  const float4* s = (const float4*)src + (size_t)q * 2;
  float4 a = s[0], b = s[1];
  union { short s8[8]; int4 v; } u;
  u.s8[0] = f2b(a.x); u.s8[1] = f2b(a.y); u.s8[2] = f2b(a.z); u.s8[3] = f2b(a.w);
  u.s8[4] = f2b(b.x); u.s8[5] = f2b(b.y); u.s8[6] = f2b(b.z); u.s8[7] = f2b(b.w);
  *(int4*)(dst + (size_t)q * 8) = u.v;
}

// ---------------- persistent weight-stationary recurrent kernel ----------------
struct RParams {
  const float* Wx;        // [L][4096][1024] f32
  const float* Wh;        // [L][4096][1024] f32
  const float* bias;      // [L][4096]
  const int*   x;         // [B][T]
  const short* embedb;    // [128][1024] bf16 (row-major)
  short* h0hist;          // [T+1][128][64][8] bf16, page t+1 = h0(t), page 0 = zeros
  short* outs;            // [T][128][64][8] bf16, page t = h1(t)
  const short* zpage;     // [128][64][8] bf16 zeros
  int* flags;             // [g*FSTR] g=0..7 group counters, [8*FSTR] root, [9*FSTR] epoch
};

__launch_bounds__(256, 1)
__global__ void lstm_recurrent(RParams P) {
  __shared__ float pLDS[4][32][36];   // per-wave partial C [32 batch x 32 gate-cols]
  __shared__ float cLDS[cB * 8];      // persistent cell state (this block's 8 h-cols)
  __shared__ float bLDS[32];

  const int tid = threadIdx.x;
  const int lane = tid & 63, wv = tid >> 6;
  const int l15 = lane & 15, lhi = lane >> 4;
  const int mh = wv >> 1;             // batch half
  const int kh = wv & 1;              // 0: Wx/x-input, 1: Wh/h-input
  const int blk = blockIdx.x;
  const int layer = blk >> 7;
  const int slice = blk & 127;
  const int hc0 = slice * 8;

  // ---- one-time: wave's 32x1024 weight slice -> registers as B-fragments ----
  bf16x8 w[2][32];
  {
    const float* Wsrc = (kh ? P.Wh : P.Wx) + (size_t)layer * c4H * cD;
    #pragma unroll
    for (int ni = 0; ni < 2; ++ni) {
      int r = ni * 16 + l15;          // output col within the 32 gate-cols
      const float* base = Wsrc + (size_t)((r >> 3) * cH + hc0 + (r & 7)) * cD + lhi * 8;
      #pragma unroll
      for (int kt = 0; kt < 32; ++kt) {
        float4 a = *(const float4*)(base + kt * 32);
        float4 b = *(const float4*)(base + kt * 32 + 4);
        union { short s8[8]; bf16x8 v; } u;
        u.s8[0] = f2b(a.x); u.s8[1] = f2b(a.y); u.s8[2] = f2b(a.z); u.s8[3] = f2b(a.w);
        u.s8[4] = f2b(b.x); u.s8[5] = f2b(b.y); u.s8[6] = f2b(b.z); u.s8[7] = f2b(b.w);
        w[ni][kt] = u.v;
      }
    }
  }
  if (tid < 32)
    bLDS[tid] = P.bias[layer * c4H + (tid >> 3) * cH + hc0 + (tid & 7)];
  for (int q = tid; q < cB * 8; q += 256) cLDS[q] = 0.0f;
  __syncthreads();

  for (int p = 0; p <= cT; ++p) {
    bool active;
    short* hout;
    const short* h0p = P.h0hist + (size_t)p * 65536;       // h0(p-1); page 0 = zeros
    const short* ahp;                                      // layer-1 Ah page
    if (layer == 0) {
      active = (p < cT);
      hout = P.h0hist + (size_t)(p + 1) * 65536;           // h0(p)
      ahp = h0p;                                           // unused placeholder
    } else {
      int t = p - 1;
      active = (t >= 0);
      int tt = t < 0 ? 0 : t;
      ahp = (t <= 0) ? P.zpage : (P.outs + (size_t)(tt - 1) * 65536);  // h1(t-1)
      hout = P.outs + (size_t)tt * 65536;
    }

    if (active) {
      // ---- per-wave A-operand base pointers ----
      const short *base0, *base1;
      int astride;
      if (layer == 0 && kh == 0) {
        // gather x-fragments straight from the 256 KB bf16 embedding table
        int xi = P.x[lane * cT + p];
        int v0 = __shfl(xi, mh * 32 + l15);
        int v1 = __shfl(xi, mh * 32 + l15 + 16);
        base0 = P.embedb + (size_t)v0 * 1024 + lhi * 8;
        base1 = P.embedb + (size_t)v1 * 1024 + lhi * 8;
        astride = 32;
      } else {
        const short* Asrc = (layer == 0) ? h0p : (kh == 0 ? h0p : ahp);
        base0 = Asrc + lhi * 512 + (mh * 32 + l15) * 8;    // slice layout
        base1 = base0 + 128;                               // row + 16
        astride = 2048;
      }

      f32x4 acc[2][2] = {};
      #pragma unroll
      for (int kt = 0; kt < 32; ++kt) {
        bf16x8 a0 = *(const bf16x8*)(base0 + kt * astride);
        bf16x8 a1 = *(const bf16x8*)(base1 + kt * astride);
        acc[0][0] = __builtin_amdgcn_mfma_f32_16x16x32_bf16(a0, w[0][kt], acc[0][0], 0, 0, 0);
        acc[0][1] = __builtin_amdgcn_mfma_f32_16x16x32_bf16(a0, w[1][kt], acc[0][1], 0, 0, 0);
        acc[1][0] = __builtin_amdgcn_mfma_f32_16x16x32_bf16(a1, w[0][kt], acc[1][0], 0, 0, 0);
        acc[1][1] = __builtin_amdgcn_mfma_f32_16x16x32_bf16(a1, w[1][kt], acc[1][1], 0, 0, 0);
      }
      #pragma unroll
      for (int mi = 0; mi < 2; ++mi)
        #pragma unroll
        for (int ni = 0; ni < 2; ++ni)
          #pragma unroll
          for (int v = 0; v < 4; ++v)
            pLDS[wv][mi * 16 + lhi * 4 + v][ni * 16 + l15] = acc[mi][ni][v];
      __syncthreads();
      // fused Wx+Wh reduction + LSTM pointwise; write-through (sc0 sc1) to block's slice
      short* houtS = hout + slice * 512;
      #pragma unroll
      for (int rep = 0; rep < 2; ++rep) {
        int e = tid + rep * 256;
        int b = e >> 3, hc = e & 7;
        int mq = (b >> 5) << 1;
        int mr = b & 31;
        float iv = pLDS[mq][mr][hc]      + pLDS[mq + 1][mr][hc]      + bLDS[hc];
        float fv = pLDS[mq][mr][8 + hc]  + pLDS[mq + 1][mr][8 + hc]  + bLDS[8 + hc];
        float gv = pLDS[mq][mr][16 + hc] + pLDS[mq + 1][mr][16 + hc] + bLDS[16 + hc];
        float ov = pLDS[mq][mr][24 + hc] + pLDS[mq + 1][mr][24 + hc] + bLDS[24 + hc];
        float cold = cLDS[e];
        float cn = sigf(fv) * cold + sigf(iv) * tanhf(gv);
        float hn = sigf(ov) * tanhf(cn);
        cLDS[e] = cn;
        unsigned hval = (unsigned)(unsigned short)f2b(hn);
        asm volatile("global_store_short %0, %1, off sc0 sc1"
                     :: "v"(houtS + e), "v"(hval) : "memory");
      }
      // drain this wave's write-through stores to the coherent point (IF$)
      asm volatile("s_waitcnt vmcnt(0)" ::: "memory");
    }

    // ---- fence-free hierarchical grid barrier (all atomics RELAXED, IF$-routed) ----
    __syncthreads();
    if (tid == 0) {
      int old = __hip_atomic_fetch_add(&P.flags[(blk & 7) * FSTR], 1,
                                       __ATOMIC_RELAXED, __HIP_MEMORY_SCOPE_AGENT);
      if (old == 32 * (p + 1) - 1) {  // last arriver of this group for phase p
        int rold = __hip_atomic_fetch_add(&P.flags[8 * FSTR], 1,
                                          __ATOMIC_RELAXED, __HIP_MEMORY_SCOPE_AGENT);
        if (rold == 8 * (p + 1) - 1)  // last group overall for phase p
          __hip_atomic_store(&P.flags[9 * FSTR], p + 1,
                             __ATOMIC_RELAXED, __HIP_MEMORY_SCOPE_AGENT);
      }
      while (__hip_atomic_load(&P.flags[9 * FSTR],
                               __ATOMIC_RELAXED, __HIP_MEMORY_SCOPE_AGENT) <= p)
        __builtin_amdgcn_s_sleep(1);
    }
    __syncthreads();
  }
}

// ---------------- output projection (outs is slice-layout) ----------------
__launch_bounds__(256, 1)
__global__ void proj_kernel(const short* __restrict__ outs, const short* __restrict__ Woutb,
                            const float* __restrict__ bout, float* __restrict__ logits) {
  const int tid = threadIdx.x, lane = tid & 63, wv = tid >> 6;
  const int l15 = lane & 15, lhi = lane >> 4;
  const int t = blockIdx.x;
  const int row = wv * 16 + l15;
  const short* Abase = outs + (size_t)t * 65536;
  f32x4 acc[8] = {};
  for (int k = 0; k < 1024; k += 32) {
    bf16x8 af = *(const bf16x8*)(Abase + ((k >> 3) + lhi) * 512 + row * 8);
    #pragma unroll
    for (int nn = 0; nn < 8; ++nn) {
      bf16x8 bf = *(const bf16x8*)(Woutb + (size_t)(nn * 16 + l15) * 1024 + k + lhi * 8);
      acc[nn] = __builtin_amdgcn_mfma_f32_16x16x32_bf16(af, bf, acc[nn], 0, 0, 0);
    }
  }
  #pragma unroll
  for (int nn = 0; nn < 8; ++nn) {
    #pragma unroll
    for (int v = 0; v < 4; ++v) {
      int b = wv * 16 + lhi * 4 + v;
      int col = nn * 16 + l15;
      logits[(size_t)b * (cT * cV) + (size_t)t * cV + col] = acc[nn][v] + bout[col];
    }
  }
}

// ---------------- launch ----------------
extern "C" void kernel_launch(void* const* d_in, const int* in_sizes, int n_in,
                              void* d_out, int out_size, void* d_ws, size_t ws_size,
                              hipStream_t stream) {
  const int* x = (const int*)d_in[0];
  const float* embed = (const float*)d_in[1];
  const float* Wx = (const float*)d_in[2];
  const float* Wh = (const float*)d_in[3];
  const float* bias = (const float*)d_in[4];
  const float* Wout = (const float*)d_in[5];
  const float* bout = (const float*)d_in[6];
  float* logits = (float*)d_out;

  char* ws = (char*)d_ws;
  size_t off = 0;
  auto alloc = [&](size_t bytes) {
    char* p = ws + off;
    off += (bytes + 255) & ~(size_t)255;
    return p;
  };
  short* Woutb  = (short*)alloc((size_t)cV * cH * 2);
  short* embedb = (short*)alloc((size_t)cV * cD * 2);
  short* outs   = (short*)alloc((size_t)cT * 65536 * 2);
  short* h0hist = (short*)alloc((size_t)(cT + 1) * 65536 * 2);
  char* state0 = ws + off;
  short* zpage  = (short*)alloc((size_t)65536 * 2);
  int* flags    = (int*)alloc((size_t)16 * FSTR * sizeof(int));
  size_t state_bytes = (size_t)((ws + off) - state0);

  hipMemsetAsync(state0, 0, state_bytes, stream);
  hipMemsetAsync(h0hist, 0, (size_t)65536 * 2, stream);   // zero initial-h page

  int n8 = cV * cH / 8;
  cvt_bf16_kernel<<<(n8 + 255) / 256, 256, 0, stream>>>(Wout, Woutb, n8);
  cvt_bf16_kernel<<<(n8 + 255) / 256, 256, 0, stream>>>(embed, embedb, n8);

  RParams P{Wx, Wh, bias, x, embedb, h0hist, outs, zpage, flags};
  lstm_recurrent<<<dim3(NBLK), dim3(256), 0, stream>>>(P);

  proj_kernel<<<cT, 256, 0, stream>>>(outs, Woutb, bout, logits);
}

// Round 6
// 9648.523 us; speedup vs baseline: 2.4206x; 1.0164x over previous
//
#include <hip/hip_runtime.h>
#include <hip/hip_bf16.h>

constexpr int cV = 128, cD = 1024, cH = 1024, cB = 64, cT = 512;
constexpr int c4H = 4096;
constexpr int NBLK = 256;
constexpr int FSTR = 32;            // flag stride in ints (128 B per slot)
constexpr int EPOCH_IDX = 256;      // flags[EPOCH_IDX*FSTR]
constexpr int BCAST0 = 260;         // flags[(BCAST0+g)*FSTR], g = blk>>3
// h pages [64][1024] stored slice-wise: [128][64][8]; addr(b,col)=(col>>3)*512+b*8+(col&7)
// page size = 65536 shorts (128 KB). Each block owns one 512-short slice region.

typedef __attribute__((ext_vector_type(8))) short bf16x8;
typedef __attribute__((ext_vector_type(4))) float f32x4;

__device__ __forceinline__ short f2b(float f) {
  __hip_bfloat16 h = __float2bfloat16(f);
  return __builtin_bit_cast(short, h);
}
__device__ __forceinline__ float sigf(float x) { return 1.0f / (1.0f + __expf(-x)); }

// ---------------- f32 -> bf16 flat converter (8 elems / thread) ----------------
__global__ void cvt_bf16_kernel(const float* __restrict__ src, short* __restrict__ dst, int n8) {
  int q = blockIdx.x * blockDim.x + threadIdx.x;
  if (q >= n8) return;
  const float4* s = (const float4*)src + (size_t)q * 2;
  float4 a = s[0], b = s[1];
  union { short s8[8]; int4 v; } u;
  u.s8[0] = f2b(a.x); u.s8[1] = f2b(a.y); u.s8[2] = f2b(a.z); u.s8[3] = f2b(a.w);
  u.s8[4] = f2b(b.x); u.s8[5] = f2b(b.y); u.s8[6] = f2b(b.z); u.s8[7] = f2b(b.w);
  *(int4*)(dst + (size_t)q * 8) = u.v;
}

// ---------------- persistent weight-stationary recurrent kernel ----------------
struct RParams {
  const float* Wx;        // [L][4096][1024] f32
  const float* Wh;        // [L][4096][1024] f32
  const float* bias;      // [L][4096]
  const int*   x;         // [B][T]
  const short* embedb;    // [128][1024] bf16 (row-major)
  short* h0hist;          // [T+1][128][64][8] bf16, page t+1 = h0(t), page 0 = zeros
  short* outs;            // [T][128][64][8] bf16, page t = h1(t)
  const short* zpage;     // [128][64][8] bf16 zeros
  int* flags;
};

__launch_bounds__(256, 1)
__global__ void lstm_recurrent(RParams P) {
  __shared__ float pLDS[4][32][36];   // per-wave partial C [32 batch x 32 gate-cols]
  __shared__ float cLDS[cB * 8];      // persistent cell state (this block's 8 h-cols)
  __shared__ float bLDS[32];

  const int tid = threadIdx.x;
  const int lane = tid & 63, wv = tid >> 6;
  const int l15 = lane & 15, lhi = lane >> 4;
  const int mh = wv >> 1;             // batch half
  const int kh = wv & 1;              // 0: Wx/x-input, 1: Wh/h-input
  const int blk = blockIdx.x;
  const int layer = blk >> 7;
  const int slice = blk & 127;
  const int hc0 = slice * 8;
  int* F = P.flags;

  // ---- one-time: wave's 32x1024 weight slice -> registers as B-fragments ----
  bf16x8 w[2][32];
  {
    const float* Wsrc = (kh ? P.Wh : P.Wx) + (size_t)layer * c4H * cD;
    #pragma unroll
    for (int ni = 0; ni < 2; ++ni) {
      int r = ni * 16 + l15;          // output col within the 32 gate-cols
      const float* base = Wsrc + (size_t)((r >> 3) * cH + hc0 + (r & 7)) * cD + lhi * 8;
      #pragma unroll
      for (int kt = 0; kt < 32; ++kt) {
        float4 a = *(const float4*)(base + kt * 32);
        float4 b = *(const float4*)(base + kt * 32 + 4);
        union { short s8[8]; bf16x8 v; } u;
        u.s8[0] = f2b(a.x); u.s8[1] = f2b(a.y); u.s8[2] = f2b(a.z); u.s8[3] = f2b(a.w);
        u.s8[4] = f2b(b.x); u.s8[5] = f2b(b.y); u.s8[6] = f2b(b.z); u.s8[7] = f2b(b.w);
        w[ni][kt] = u.v;
      }
    }
  }
  if (tid < 32)
    bLDS[tid] = P.bias[layer * c4H + (tid >> 3) * cH + hc0 + (tid & 7)];
  for (int q = tid; q < cB * 8; q += 256) cLDS[q] = 0.0f;
  __syncthreads();

  // ---- L0/kh==0 bootstrap: x-part accumulators for phase 0 ----
  f32x4 accx[2][2] = {};
  if (layer == 0 && kh == 0) {
    int xi = P.x[lane * cT + 0];
    int v0 = __shfl(xi, mh * 32 + l15);
    int v1 = __shfl(xi, mh * 32 + l15 + 16);
    const short* b0 = P.embedb + (size_t)v0 * 1024 + lhi * 8;
    const short* b1 = P.embedb + (size_t)v1 * 1024 + lhi * 8;
    #pragma unroll
    for (int kt = 0; kt < 32; ++kt) {
      bf16x8 a0 = *(const bf16x8*)(b0 + kt * 32);
      bf16x8 a1 = *(const bf16x8*)(b1 + kt * 32);
      accx[0][0] = __builtin_amdgcn_mfma_f32_16x16x32_bf16(a0, w[0][kt], accx[0][0], 0, 0, 0);
      accx[0][1] = __builtin_amdgcn_mfma_f32_16x16x32_bf16(a0, w[1][kt], accx[0][1], 0, 0, 0);
      accx[1][0] = __builtin_amdgcn_mfma_f32_16x16x32_bf16(a1, w[0][kt], accx[1][0], 0, 0, 0);
      accx[1][1] = __builtin_amdgcn_mfma_f32_16x16x32_bf16(a1, w[1][kt], accx[1][1], 0, 0, 0);
    }
  }

  for (int p = 0; p <= cT; ++p) {
    bool active;
    short* hout;
    const short* h0p = P.h0hist + (size_t)p * 65536;       // h0(p-1); page 0 = zeros
    const short* ahp = h0p;
    if (layer == 0) {
      active = (p < cT);
      hout = P.h0hist + (size_t)(p + 1) * 65536;           // h0(p)
    } else {
      int t = p - 1;
      active = (t >= 0);
      int tt = t < 0 ? 0 : t;
      ahp = (t <= 0) ? P.zpage : (P.outs + (size_t)(tt - 1) * 65536);  // h1(t-1)
      hout = P.outs + (size_t)tt * 65536;
    }

    if (active) {
      f32x4 acc[2][2] = {};
      bool useAccx = (layer == 0 && kh == 0);
      if (!useAccx) {
        // critical-path GEMM: L0/kh1 -> Wh0@h0(p-1); L1 -> Wx1@h0(t) or Wh1@h1(t-1)
        const short* Asrc = (layer == 0) ? h0p : (kh == 0 ? h0p : ahp);
        const short* base0 = Asrc + lhi * 512 + (mh * 32 + l15) * 8;   // slice layout
        const short* base1 = base0 + 128;                              // row + 16
        #pragma unroll
        for (int kt = 0; kt < 32; ++kt) {
          bf16x8 a0 = *(const bf16x8*)(base0 + kt * 2048);
          bf16x8 a1 = *(const bf16x8*)(base1 + kt * 2048);
          acc[0][0] = __builtin_amdgcn_mfma_f32_16x16x32_bf16(a0, w[0][kt], acc[0][0], 0, 0, 0);
          acc[0][1] = __builtin_amdgcn_mfma_f32_16x16x32_bf16(a0, w[1][kt], acc[0][1], 0, 0, 0);
          acc[1][0] = __builtin_amdgcn_mfma_f32_16x16x32_bf16(a1, w[0][kt], acc[1][0], 0, 0, 0);
          acc[1][1] = __builtin_amdgcn_mfma_f32_16x16x32_bf16(a1, w[1][kt], acc[1][1], 0, 0, 0);
        }
      }
      #pragma unroll
      for (int mi = 0; mi < 2; ++mi)
        #pragma unroll
        for (int ni = 0; ni < 2; ++ni)
          #pragma unroll
          for (int v = 0; v < 4; ++v)
            pLDS[wv][mi * 16 + lhi * 4 + v][ni * 16 + l15] =
                useAccx ? accx[mi][ni][v] : acc[mi][ni][v];
      __syncthreads();
      // fused x+h reduction + LSTM pointwise; write-through (sc0 sc1) to block's slice
      short* houtS = hout + slice * 512;
      #pragma unroll
      for (int rep = 0; rep < 2; ++rep) {
        int e = tid + rep * 256;
        int b = e >> 3, hc = e & 7;
        int mq = (b >> 5) << 1;
        int mr = b & 31;
        float iv = pLDS[mq][mr][hc]      + pLDS[mq + 1][mr][hc]      + bLDS[hc];
        float fv = pLDS[mq][mr][8 + hc]  + pLDS[mq + 1][mr][8 + hc]  + bLDS[8 + hc];
        float gv = pLDS[mq][mr][16 + hc] + pLDS[mq + 1][mr][16 + hc] + bLDS[16 + hc];
        float ov = pLDS[mq][mr][24 + hc] + pLDS[mq + 1][mr][24 + hc] + bLDS[24 + hc];
        float cold = cLDS[e];
        float cn = sigf(fv) * cold + sigf(iv) * tanhf(gv);
        float hn = sigf(ov) * tanhf(cn);
        cLDS[e] = cn;
        unsigned hval = (unsigned)(unsigned short)f2b(hn);
        asm volatile("global_store_short %0, %1, off sc0 sc1"
                     :: "v"(houtS + e), "v"(hval) : "memory");
      }
      // drain this wave's write-through stores to the coherent point (IF$)
      asm volatile("s_waitcnt vmcnt(0)" ::: "memory");
    }

    __syncthreads();   // all h-stores of this block drained
    const int tgt = p + 1;
    if (tid == 64)     // single-writer arrival word (plain relaxed store, no RMW)
      __hip_atomic_store(&F[blk * FSTR], tgt, __ATOMIC_RELAXED, __HIP_MEMORY_SCOPE_AGENT);

    // ---- useful-wait: L0 x-waves compute next phase's x-part during the sync ----
    if (layer == 0 && kh == 0 && tgt < cT) {
      #pragma unroll
      for (int mi = 0; mi < 2; ++mi)
        #pragma unroll
        for (int ni = 0; ni < 2; ++ni)
          accx[mi][ni] = (f32x4){0.f, 0.f, 0.f, 0.f};
      int xi = P.x[lane * cT + tgt];
      int v0 = __shfl(xi, mh * 32 + l15);
      int v1 = __shfl(xi, mh * 32 + l15 + 16);
      const short* b0 = P.embedb + (size_t)v0 * 1024 + lhi * 8;
      const short* b1 = P.embedb + (size_t)v1 * 1024 + lhi * 8;
      #pragma unroll
      for (int kt = 0; kt < 32; ++kt) {
        bf16x8 a0 = *(const bf16x8*)(b0 + kt * 32);
        bf16x8 a1 = *(const bf16x8*)(b1 + kt * 32);
        accx[0][0] = __builtin_amdgcn_mfma_f32_16x16x32_bf16(a0, w[0][kt], accx[0][0], 0, 0, 0);
        accx[0][1] = __builtin_amdgcn_mfma_f32_16x16x32_bf16(a0, w[1][kt], accx[0][1], 0, 0, 0);
        accx[1][0] = __builtin_amdgcn_mfma_f32_16x16x32_bf16(a1, w[0][kt], accx[1][0], 0, 0, 0);
        accx[1][1] = __builtin_amdgcn_mfma_f32_16x16x32_bf16(a1, w[1][kt], accx[1][1], 0, 0, 0);
      }
    }

    // ---- barrier wait (wave 1 only; kh=1 wave, free during the wait) ----
    if (wv == 1) {
      if (blk == 0) {
        // root: full-wave sweep over 256 arrival words (4 pipelined loads/lane)
        bool done = false;
        while (!done) {
          int a0 = __hip_atomic_load(&F[lane * FSTR],         __ATOMIC_RELAXED, __HIP_MEMORY_SCOPE_AGENT);
          int a1 = __hip_atomic_load(&F[(lane + 64) * FSTR],  __ATOMIC_RELAXED, __HIP_MEMORY_SCOPE_AGENT);
          int a2 = __hip_atomic_load(&F[(lane + 128) * FSTR], __ATOMIC_RELAXED, __HIP_MEMORY_SCOPE_AGENT);
          int a3 = __hip_atomic_load(&F[(lane + 192) * FSTR], __ATOMIC_RELAXED, __HIP_MEMORY_SCOPE_AGENT);
          done = __all(a0 >= tgt && a1 >= tgt && a2 >= tgt && a3 >= tgt);
          if (!done) __builtin_amdgcn_s_sleep(1);
        }
        if (lane == 0) {
          __hip_atomic_store(&F[EPOCH_IDX * FSTR], tgt, __ATOMIC_RELAXED, __HIP_MEMORY_SCOPE_AGENT);
          __hip_atomic_store(&F[BCAST0 * FSTR],    tgt, __ATOMIC_RELAXED, __HIP_MEMORY_SCOPE_AGENT);
        }
      } else if ((blk & 7) == 0) {
        // leader: poll epoch (fan-in 32), relay to group line (fan-in 7)
        if (lane == 0) {
          while (__hip_atomic_load(&F[EPOCH_IDX * FSTR],
                                   __ATOMIC_RELAXED, __HIP_MEMORY_SCOPE_AGENT) < tgt)
            __builtin_amdgcn_s_sleep(1);
          __hip_atomic_store(&F[(BCAST0 + (blk >> 3)) * FSTR], tgt,
                             __ATOMIC_RELAXED, __HIP_MEMORY_SCOPE_AGENT);
        }
      } else {
        if (lane == 0) {
          while (__hip_atomic_load(&F[(BCAST0 + (blk >> 3)) * FSTR],
                                   __ATOMIC_RELAXED, __HIP_MEMORY_SCOPE_AGENT) < tgt)
            __builtin_amdgcn_s_sleep(1);
        }
      }
    }
    __syncthreads();
  }
}

// ---------------- output projection (outs is slice-layout) ----------------
__launch_bounds__(256, 1)
__global__ void proj_kernel(const short* __restrict__ outs, const short* __restrict__ Woutb,
                            const float* __restrict__ bout, float* __restrict__ logits) {
  const int tid = threadIdx.x, lane = tid & 63, wv = tid >> 6;
  const int l15 = lane & 15, lhi = lane >> 4;
  const int t = blockIdx.x;
  const int row = wv * 16 + l15;
  const short* Abase = outs + (size_t)t * 65536;
  f32x4 acc[8] = {};
  for (int k = 0; k < 1024; k += 32) {
    bf16x8 af = *(const bf16x8*)(Abase + ((k >> 3) + lhi) * 512 + row * 8);
    #pragma unroll
    for (int nn = 0; nn < 8; ++nn) {
      bf16x8 bf = *(const bf16x8*)(Woutb + (size_t)(nn * 16 + l15) * 1024 + k + lhi * 8);
      acc[nn] = __builtin_amdgcn_mfma_f32_16x16x32_bf16(af, bf, acc[nn], 0, 0, 0);
    }
  }
  #pragma unroll
  for (int nn = 0; nn < 8; ++nn) {
    #pragma unroll
    for (int v = 0; v < 4; ++v) {
      int b = wv * 16 + lhi * 4 + v;
      int col = nn * 16 + l15;
      logits[(size_t)b * (cT * cV) + (size_t)t * cV + col] = acc[nn][v] + bout[col];
    }
  }
}

// ---------------- launch ----------------
extern "C" void kernel_launch(void* const* d_in, const int* in_sizes, int n_in,
                              void* d_out, int out_size, void* d_ws, size_t ws_size,
                              hipStream_t stream) {
  const int* x = (const int*)d_in[0];
  const float* embed = (const float*)d_in[1];
  const float* Wx = (const float*)d_in[2];
  const float* Wh = (const float*)d_in[3];
  const float* bias = (const float*)d_in[4];
  const float* Wout = (const float*)d_in[5];
  const float* bout = (const float*)d_in[6];
  float* logits = (float*)d_out;

  char* ws = (char*)d_ws;
  size_t off = 0;
  auto alloc = [&](size_t bytes) {
    char* p = ws + off;
    off += (bytes + 255) & ~(size_t)255;
    return p;
  };
  short* Woutb  = (short*)alloc((size_t)cV * cH * 2);
  short* embedb = (short*)alloc((size_t)cV * cD * 2);
  short* outs   = (short*)alloc((size_t)cT * 65536 * 2);
  short* h0hist = (short*)alloc((size_t)(cT + 1) * 65536 * 2);
  char* state0 = ws + off;
  short* zpage  = (short*)alloc((size_t)65536 * 2);
  int* flags    = (int*)alloc((size_t)300 * FSTR * sizeof(int));
  size_t state_bytes = (size_t)((ws + off) - state0);

  hipMemsetAsync(state0, 0, state_bytes, stream);
  hipMemsetAsync(h0hist, 0, (size_t)65536 * 2, stream);   // zero initial-h page

  int n8 = cV * cH / 8;
  cvt_bf16_kernel<<<(n8 + 255) / 256, 256, 0, stream>>>(Wout, Woutb, n8);
  cvt_bf16_kernel<<<(n8 + 255) / 256, 256, 0, stream>>>(embed, embedb, n8);

  RParams P{Wx, Wh, bias, x, embedb, h0hist, outs, zpage, flags};
  lstm_recurrent<<<dim3(NBLK), dim3(256), 0, stream>>>(P);

  proj_kernel<<<cT, 256, 0, stream>>>(outs, Woutb, bout, logits);
}

// Round 7
// 9540.467 us; speedup vs baseline: 2.4480x; 1.0113x over previous
//
#include <hip/hip_runtime.h>
#include <hip/hip_bf16.h>

constexpr int cV = 128, cD = 1024, cH = 1024, cB = 64, cT = 512;
constexpr int c4H = 4096;
constexpr int NBLK = 256;
constexpr int FSTR = 32;            // flag stride in ints (128 B per slot)
// h pages [64][1024] stored slice-wise: [128][64][8]; addr(b,col)=(col>>3)*512+b*8+(col&7)
// page size = 65536 shorts (128 KB). Each block owns one 512-short slice region.

typedef __attribute__((ext_vector_type(8))) short bf16x8;
typedef __attribute__((ext_vector_type(4))) float f32x4;
typedef __attribute__((ext_vector_type(4))) int i32x4;

__device__ __forceinline__ short f2b(float f) {
  __hip_bfloat16 h = __float2bfloat16(f);
  return __builtin_bit_cast(short, h);
}
__device__ __forceinline__ float sigf(float x) { return 1.0f / (1.0f + __expf(-x)); }

// ---------------- f32 -> bf16 flat converter (8 elems / thread) ----------------
__global__ void cvt_bf16_kernel(const float* __restrict__ src, short* __restrict__ dst, int n8) {
  int q = blockIdx.x * blockDim.x + threadIdx.x;
  if (q >= n8) return;
  const float4* s = (const float4*)src + (size_t)q * 2;
  float4 a = s[0], b = s[1];
  union { short s8[8]; int4 v; } u;
  u.s8[0] = f2b(a.x); u.s8[1] = f2b(a.y); u.s8[2] = f2b(a.z); u.s8[3] = f2b(a.w);
  u.s8[4] = f2b(b.x); u.s8[5] = f2b(b.y); u.s8[6] = f2b(b.z); u.s8[7] = f2b(b.w);
  *(int4*)(dst + (size_t)q * 8) = u.v;
}

// ---------------- persistent weight-stationary recurrent kernel ----------------
struct RParams {
  const float* Wx;        // [L][4096][1024] f32
  const float* Wh;        // [L][4096][1024] f32
  const float* bias;      // [L][4096]
  const int*   x;         // [B][T]
  const short* embedb;    // [128][1024] bf16 (row-major)
  short* h0hist;          // [T+1][128][64][8] bf16, page t+1 = h0(t), page 0 = zeros
  short* outs;            // [T][128][64][8] bf16, page t = h1(t)
  const short* zpage;     // [128][64][8] bf16 zeros
  int* flags;             // [256*FSTR] per-block arrival words (single-writer)
};

__launch_bounds__(256, 1)
__global__ void lstm_recurrent(RParams P) {
  __shared__ float pLDS[4][32][36];   // per-wave partial C [32 batch x 32 gate-cols]
  __shared__ float cLDS[cB * 8];      // persistent cell state (this block's 8 h-cols)
  __shared__ float bLDS[32];
  __shared__ short hLDS[cB * 8];      // staged h outputs for coalesced writeback

  const int tid = threadIdx.x;
  const int lane = tid & 63, wv = tid >> 6;
  const int l15 = lane & 15, lhi = lane >> 4;
  const int mh = wv >> 1;             // batch half
  const int kh = wv & 1;              // 0: Wx/x-input, 1: Wh/h-input
  const int blk = blockIdx.x;
  const int layer = blk >> 7;
  const int slice = blk & 127;
  const int hc0 = slice * 8;
  int* F = P.flags;

  // ---- one-time: wave's 32x1024 weight slice -> registers as B-fragments ----
  bf16x8 w[2][32];
  {
    const float* Wsrc = (kh ? P.Wh : P.Wx) + (size_t)layer * c4H * cD;
    #pragma unroll
    for (int ni = 0; ni < 2; ++ni) {
      int r = ni * 16 + l15;          // output col within the 32 gate-cols
      const float* base = Wsrc + (size_t)((r >> 3) * cH + hc0 + (r & 7)) * cD + lhi * 8;
      #pragma unroll
      for (int kt = 0; kt < 32; ++kt) {
        float4 a = *(const float4*)(base + kt * 32);
        float4 b = *(const float4*)(base + kt * 32 + 4);
        union { short s8[8]; bf16x8 v; } u;
        u.s8[0] = f2b(a.x); u.s8[1] = f2b(a.y); u.s8[2] = f2b(a.z); u.s8[3] = f2b(a.w);
        u.s8[4] = f2b(b.x); u.s8[5] = f2b(b.y); u.s8[6] = f2b(b.z); u.s8[7] = f2b(b.w);
        w[ni][kt] = u.v;
      }
    }
  }
  if (tid < 32)
    bLDS[tid] = P.bias[layer * c4H + (tid >> 3) * cH + hc0 + (tid & 7)];
  for (int q = tid; q < cB * 8; q += 256) cLDS[q] = 0.0f;
  __syncthreads();

  // ---- L0/kh==0 bootstrap: x-part accumulators for phase 0 ----
  f32x4 accx[2][2] = {};
  if (layer == 0 && kh == 0) {
    int xi = P.x[lane * cT + 0];
    int v0 = __shfl(xi, mh * 32 + l15);
    int v1 = __shfl(xi, mh * 32 + l15 + 16);
    const short* b0 = P.embedb + (size_t)v0 * 1024 + lhi * 8;
    const short* b1 = P.embedb + (size_t)v1 * 1024 + lhi * 8;
    #pragma unroll
    for (int kt = 0; kt < 32; ++kt) {
      bf16x8 a0 = *(const bf16x8*)(b0 + kt * 32);
      bf16x8 a1 = *(const bf16x8*)(b1 + kt * 32);
      accx[0][0] = __builtin_amdgcn_mfma_f32_16x16x32_bf16(a0, w[0][kt], accx[0][0], 0, 0, 0);
      accx[0][1] = __builtin_amdgcn_mfma_f32_16x16x32_bf16(a0, w[1][kt], accx[0][1], 0, 0, 0);
      accx[1][0] = __builtin_amdgcn_mfma_f32_16x16x32_bf16(a1, w[0][kt], accx[1][0], 0, 0, 0);
      accx[1][1] = __builtin_amdgcn_mfma_f32_16x16x32_bf16(a1, w[1][kt], accx[1][1], 0, 0, 0);
    }
  }

  for (int p = 0; p <= cT; ++p) {
    bool active;
    short* hout;
    const short* h0p = P.h0hist + (size_t)p * 65536;       // h0(p-1); page 0 = zeros
    const short* ahp = h0p;
    if (layer == 0) {
      active = (p < cT);
      hout = P.h0hist + (size_t)(p + 1) * 65536;           // h0(p)
    } else {
      int t = p - 1;
      active = (t >= 0);
      int tt = t < 0 ? 0 : t;
      ahp = (t <= 0) ? P.zpage : (P.outs + (size_t)(tt - 1) * 65536);  // h1(t-1)
      hout = P.outs + (size_t)tt * 65536;
    }

    if (active) {
      f32x4 acc[2][2] = {};
      bool useAccx = (layer == 0 && kh == 0);
      if (!useAccx) {
        // critical-path GEMM: L0/kh1 -> Wh0@h0(p-1); L1 -> Wx1@h0(t) or Wh1@h1(t-1)
        const short* Asrc = (layer == 0) ? h0p : (kh == 0 ? h0p : ahp);
        const short* base0 = Asrc + lhi * 512 + (mh * 32 + l15) * 8;   // slice layout
        const short* base1 = base0 + 128;                              // row + 16
        #pragma unroll
        for (int kt = 0; kt < 32; ++kt) {
          bf16x8 a0 = *(const bf16x8*)(base0 + kt * 2048);
          bf16x8 a1 = *(const bf16x8*)(base1 + kt * 2048);
          acc[0][0] = __builtin_amdgcn_mfma_f32_16x16x32_bf16(a0, w[0][kt], acc[0][0], 0, 0, 0);
          acc[0][1] = __builtin_amdgcn_mfma_f32_16x16x32_bf16(a0, w[1][kt], acc[0][1], 0, 0, 0);
          acc[1][0] = __builtin_amdgcn_mfma_f32_16x16x32_bf16(a1, w[0][kt], acc[1][0], 0, 0, 0);
          acc[1][1] = __builtin_amdgcn_mfma_f32_16x16x32_bf16(a1, w[1][kt], acc[1][1], 0, 0, 0);
        }
      }
      #pragma unroll
      for (int mi = 0; mi < 2; ++mi)
        #pragma unroll
        for (int ni = 0; ni < 2; ++ni)
          #pragma unroll
          for (int v = 0; v < 4; ++v)
            pLDS[wv][mi * 16 + lhi * 4 + v][ni * 16 + l15] =
                useAccx ? accx[mi][ni][v] : acc[mi][ni][v];
      __syncthreads();
      // fused x+h reduction + LSTM pointwise -> hLDS staging (no global traffic here)
      #pragma unroll
      for (int rep = 0; rep < 2; ++rep) {
        int e = tid + rep * 256;
        int b = e >> 3, hc = e & 7;
        int mq = (b >> 5) << 1;
        int mr = b & 31;
        float iv = pLDS[mq][mr][hc]      + pLDS[mq + 1][mr][hc]      + bLDS[hc];
        float fv = pLDS[mq][mr][8 + hc]  + pLDS[mq + 1][mr][8 + hc]  + bLDS[8 + hc];
        float gv = pLDS[mq][mr][16 + hc] + pLDS[mq + 1][mr][16 + hc] + bLDS[16 + hc];
        float ov = pLDS[mq][mr][24 + hc] + pLDS[mq + 1][mr][24 + hc] + bLDS[24 + hc];
        float cold = cLDS[e];
        float cn = sigf(fv) * cold + sigf(iv) * tanhf(gv);
        float hn = sigf(ov) * tanhf(cn);
        cLDS[e] = cn;
        hLDS[e] = f2b(hn);
      }
    }

    __syncthreads();   // hLDS complete (also joins !active blocks)
    const int tgt = p + 1;

    // ---- coalesced write-through h writeback (wave 0: 64 x 16B packets) ----
    if (wv == 0) {
      if (active) {
        short* houtS = hout + slice * 512;
        i32x4 hv = *(const i32x4*)&hLDS[lane * 8];
        asm volatile("global_store_dwordx4 %0, %1, off sc0 sc1"
                     :: "v"(houtS + lane * 8), "v"(hv) : "memory");
        asm volatile("s_waitcnt vmcnt(0)" ::: "memory");   // drained to coherent point
      }
      if (lane == 0)   // single-writer arrival word (plain relaxed store)
        __hip_atomic_store(&F[blk * FSTR], tgt, __ATOMIC_RELAXED, __HIP_MEMORY_SCOPE_AGENT);
    }

    // ---- useful-wait: L0 x-waves compute next phase's x-part during the sync ----
    if (layer == 0 && kh == 0 && tgt < cT) {
      #pragma unroll
      for (int mi = 0; mi < 2; ++mi)
        #pragma unroll
        for (int ni = 0; ni < 2; ++ni)
          accx[mi][ni] = (f32x4){0.f, 0.f, 0.f, 0.f};
      int xi = P.x[lane * cT + tgt];
      int v0 = __shfl(xi, mh * 32 + l15);
      int v1 = __shfl(xi, mh * 32 + l15 + 16);
      const short* b0 = P.embedb + (size_t)v0 * 1024 + lhi * 8;
      const short* b1 = P.embedb + (size_t)v1 * 1024 + lhi * 8;
      #pragma unroll
      for (int kt = 0; kt < 32; ++kt) {
        bf16x8 a0 = *(const bf16x8*)(b0 + kt * 32);
        bf16x8 a1 = *(const bf16x8*)(b1 + kt * 32);
        accx[0][0] = __builtin_amdgcn_mfma_f32_16x16x32_bf16(a0, w[0][kt], accx[0][0], 0, 0, 0);
        accx[0][1] = __builtin_amdgcn_mfma_f32_16x16x32_bf16(a0, w[1][kt], accx[0][1], 0, 0, 0);
        accx[1][0] = __builtin_amdgcn_mfma_f32_16x16x32_bf16(a1, w[0][kt], accx[1][0], 0, 0, 0);
        accx[1][1] = __builtin_amdgcn_mfma_f32_16x16x32_bf16(a1, w[1][kt], accx[1][1], 0, 0, 0);
      }
    }

    // ---- single-hop barrier: wave 1 sweeps arrival words directly ----
    // L0 blocks depend only on L0 (words 0-127); L1 blocks depend on both (0-255).
    if (wv == 1) {
      if (layer == 0) {
        bool done = false;
        while (!done) {
          int a0 = __hip_atomic_load(&F[lane * FSTR],        __ATOMIC_RELAXED, __HIP_MEMORY_SCOPE_AGENT);
          int a1 = __hip_atomic_load(&F[(lane + 64) * FSTR], __ATOMIC_RELAXED, __HIP_MEMORY_SCOPE_AGENT);
          done = __all(a0 >= tgt && a1 >= tgt);
          if (!done) __builtin_amdgcn_s_sleep(1);
        }
      } else {
        bool done = false;
        while (!done) {
          int a0 = __hip_atomic_load(&F[lane * FSTR],         __ATOMIC_RELAXED, __HIP_MEMORY_SCOPE_AGENT);
          int a1 = __hip_atomic_load(&F[(lane + 64) * FSTR],  __ATOMIC_RELAXED, __HIP_MEMORY_SCOPE_AGENT);
          int a2 = __hip_atomic_load(&F[(lane + 128) * FSTR], __ATOMIC_RELAXED, __HIP_MEMORY_SCOPE_AGENT);
          int a3 = __hip_atomic_load(&F[(lane + 192) * FSTR], __ATOMIC_RELAXED, __HIP_MEMORY_SCOPE_AGENT);
          done = __all(a0 >= tgt && a1 >= tgt && a2 >= tgt && a3 >= tgt);
          if (!done) __builtin_amdgcn_s_sleep(1);
        }
      }
    }
    __syncthreads();
  }
}

// ---------------- output projection (outs is slice-layout) ----------------
__launch_bounds__(256, 1)
__global__ void proj_kernel(const short* __restrict__ outs, const short* __restrict__ Woutb,
                            const float* __restrict__ bout, float* __restrict__ logits) {
  const int tid = threadIdx.x, lane = tid & 63, wv = tid >> 6;
  const int l15 = lane & 15, lhi = lane >> 4;
  const int t = blockIdx.x;
  const int row = wv * 16 + l15;
  const short* Abase = outs + (size_t)t * 65536;
  f32x4 acc[8] = {};
  for (int k = 0; k < 1024; k += 32) {
    bf16x8 af = *(const bf16x8*)(Abase + ((k >> 3) + lhi) * 512 + row * 8);
    #pragma unroll
    for (int nn = 0; nn < 8; ++nn) {
      bf16x8 bf = *(const bf16x8*)(Woutb + (size_t)(nn * 16 + l15) * 1024 + k + lhi * 8);
      acc[nn] = __builtin_amdgcn_mfma_f32_16x16x32_bf16(af, bf, acc[nn], 0, 0, 0);
    }
  }
  #pragma unroll
  for (int nn = 0; nn < 8; ++nn) {
    #pragma unroll
    for (int v = 0; v < 4; ++v) {
      int b = wv * 16 + lhi * 4 + v;
      int col = nn * 16 + l15;
      logits[(size_t)b * (cT * cV) + (size_t)t * cV + col] = acc[nn][v] + bout[col];
    }
  }
}

// ---------------- launch ----------------
extern "C" void kernel_launch(void* const* d_in, const int* in_sizes, int n_in,
                              void* d_out, int out_size, void* d_ws, size_t ws_size,
                              hipStream_t stream) {
  const int* x = (const int*)d_in[0];
  const float* embed = (const float*)d_in[1];
  const float* Wx = (const float*)d_in[2];
  const float* Wh = (const float*)d_in[3];
  const float* bias = (const float*)d_in[4];
  const float* Wout = (const float*)d_in[5];
  const float* bout = (const float*)d_in[6];
  float* logits = (float*)d_out;

  char* ws = (char*)d_ws;
  size_t off = 0;
  auto alloc = [&](size_t bytes) {
    char* p = ws + off;
    off += (bytes + 255) & ~(size_t)255;
    return p;
  };
  short* Woutb  = (short*)alloc((size_t)cV * cH * 2);
  short* embedb = (short*)alloc((size_t)cV * cD * 2);
  short* outs   = (short*)alloc((size_t)cT * 65536 * 2);
  short* h0hist = (short*)alloc((size_t)(cT + 1) * 65536 * 2);
  char* state0 = ws + off;
  short* zpage  = (short*)alloc((size_t)65536 * 2);
  int* flags    = (int*)alloc((size_t)NBLK * FSTR * sizeof(int));
  size_t state_bytes = (size_t)((ws + off) - state0);

  hipMemsetAsync(state0, 0, state_bytes, stream);
  hipMemsetAsync(h0hist, 0, (size_t)65536 * 2, stream);   // zero initial-h page

  int n8 = cV * cH / 8;
  cvt_bf16_kernel<<<(n8 + 255) / 256, 256, 0, stream>>>(Wout, Woutb, n8);
  cvt_bf16_kernel<<<(n8 + 255) / 256, 256, 0, stream>>>(embed, embedb, n8);

  RParams P{Wx, Wh, bias, x, embedb, h0hist, outs, zpage, flags};
  lstm_recurrent<<<dim3(NBLK), dim3(256), 0, stream>>>(P);

  proj_kernel<<<cT, 256, 0, stream>>>(outs, Woutb, bout, logits);
}

// Round 8
// 6873.769 us; speedup vs baseline: 3.3978x; 1.3880x over previous
//
#include <hip/hip_runtime.h>
#include <hip/hip_bf16.h>

constexpr int cV = 128, cD = 1024, cH = 1024, cB = 64, cT = 512;
constexpr int c4H = 4096;
constexpr int NBLK = 256;
constexpr int FSTR = 32;            // flag stride in ints (128 B per slot)
// h pages [64][1024] stored slice-wise: [128][64][8]; addr(b,col)=(col>>3)*512+b*8+(col&7)
// page size = 65536 shorts (128 KB). Each block owns one 512-short slice region.

typedef __attribute__((ext_vector_type(8))) short bf16x8;
typedef __attribute__((ext_vector_type(4))) float f32x4;
typedef __attribute__((ext_vector_type(4))) int i32x4;

__device__ __forceinline__ short f2b(float f) {
  __hip_bfloat16 h = __float2bfloat16(f);
  return __builtin_bit_cast(short, h);
}
__device__ __forceinline__ float sigf(float x) { return 1.0f / (1.0f + __expf(-x)); }

// async global->LDS, 16B per lane; per-wave LDS dest must be base + lane*16 (it is: tid-linear)
__device__ __forceinline__ void gload16(const short* g, short* l) {
  __builtin_amdgcn_global_load_lds(
      (const __attribute__((address_space(1))) void*)g,
      (__attribute__((address_space(3))) void*)l, 16, 0, 0);
}

// ---------------- f32 -> bf16 flat converter (8 elems / thread) ----------------
__global__ void cvt_bf16_kernel(const float* __restrict__ src, short* __restrict__ dst, int n8) {
  int q = blockIdx.x * blockDim.x + threadIdx.x;
  if (q >= n8) return;
  const float4* s = (const float4*)src + (size_t)q * 2;
  float4 a = s[0], b = s[1];
  union { short s8[8]; int4 v; } u;
  u.s8[0] = f2b(a.x); u.s8[1] = f2b(a.y); u.s8[2] = f2b(a.z); u.s8[3] = f2b(a.w);
  u.s8[4] = f2b(b.x); u.s8[5] = f2b(b.y); u.s8[6] = f2b(b.z); u.s8[7] = f2b(b.w);
  *(int4*)(dst + (size_t)q * 8) = u.v;
}

// ---------------- persistent weight-stationary recurrent kernel ----------------
struct RParams {
  const float* Wx;        // [L][4096][1024] f32
  const float* Wh;        // [L][4096][1024] f32
  const float* bias;      // [L][4096]
  const int*   x;         // [B][T]
  const short* embedb;    // [128][1024] bf16 (row-major)
  short* h0hist;          // [T+1][128][64][8] bf16, page t+1 = h0(t), page 0 = zeros
  short* outs;            // [T][128][64][8] bf16, page t = h1(t)
  const short* zpage;     // [128][64][8] bf16 zeros
  int* flags;             // [256*FSTR] per-block arrival words (single-writer)
};

__launch_bounds__(256, 1)
__global__ void lstm_recurrent(RParams P) {
  __shared__ __align__(16) short sLDS[4][16384]; // A staging: L0 flat 128KB; L1 2buf x {op0,op1}
  __shared__ float pLDS[4][32][36];   // per-wave partial C [32 batch x 32 gate-cols]
  __shared__ float cLDS[cB * 8];      // persistent cell state (this block's 8 h-cols)
  __shared__ float bLDS[32];
  __shared__ short hLDS[cB * 8];      // staged h outputs for coalesced writeback

  const int tid = threadIdx.x;
  const int lane = tid & 63, wv = tid >> 6;
  const int l15 = lane & 15, lhi = lane >> 4;
  const int mh = wv >> 1;             // batch half
  const int kh = wv & 1;              // 0: Wx/x-input, 1: Wh/h-input
  const int blk = blockIdx.x;
  const int layer = blk >> 7;
  const int slice = blk & 127;
  const int hc0 = slice * 8;
  int* F = P.flags;

  // ---- one-time: wave's 32x1024 weight slice -> registers as B-fragments ----
  bf16x8 w[2][32];
  {
    const float* Wsrc = (kh ? P.Wh : P.Wx) + (size_t)layer * c4H * cD;
    #pragma unroll
    for (int ni = 0; ni < 2; ++ni) {
      int r = ni * 16 + l15;          // output col within the 32 gate-cols
      const float* base = Wsrc + (size_t)((r >> 3) * cH + hc0 + (r & 7)) * cD + lhi * 8;
      #pragma unroll
      for (int kt = 0; kt < 32; ++kt) {
        float4 a = *(const float4*)(base + kt * 32);
        float4 b = *(const float4*)(base + kt * 32 + 4);
        union { short s8[8]; bf16x8 v; } u;
        u.s8[0] = f2b(a.x); u.s8[1] = f2b(a.y); u.s8[2] = f2b(a.z); u.s8[3] = f2b(a.w);
        u.s8[4] = f2b(b.x); u.s8[5] = f2b(b.y); u.s8[6] = f2b(b.z); u.s8[7] = f2b(b.w);
        w[ni][kt] = u.v;
      }
    }
  }
  if (tid < 32)
    bLDS[tid] = P.bias[layer * c4H + (tid >> 3) * cH + hc0 + (tid & 7)];
  for (int q = tid; q < cB * 8; q += 256) cLDS[q] = 0.0f;
  __syncthreads();

  // ---- L0/kh==0 bootstrap: x-part accumulators for phase 0 ----
  f32x4 accx[2][2] = {};
  if (layer == 0 && kh == 0) {
    int xi = P.x[lane * cT + 0];
    int v0 = __shfl(xi, mh * 32 + l15);
    int v1 = __shfl(xi, mh * 32 + l15 + 16);
    const short* b0 = P.embedb + (size_t)v0 * 1024 + lhi * 8;
    const short* b1 = P.embedb + (size_t)v1 * 1024 + lhi * 8;
    #pragma unroll
    for (int kt = 0; kt < 32; ++kt) {
      bf16x8 a0 = *(const bf16x8*)(b0 + kt * 32);
      bf16x8 a1 = *(const bf16x8*)(b1 + kt * 32);
      accx[0][0] = __builtin_amdgcn_mfma_f32_16x16x32_bf16(a0, w[0][kt], accx[0][0], 0, 0, 0);
      accx[0][1] = __builtin_amdgcn_mfma_f32_16x16x32_bf16(a0, w[1][kt], accx[0][1], 0, 0, 0);
      accx[1][0] = __builtin_amdgcn_mfma_f32_16x16x32_bf16(a1, w[0][kt], accx[1][0], 0, 0, 0);
      accx[1][1] = __builtin_amdgcn_mfma_f32_16x16x32_bf16(a1, w[1][kt], accx[1][1], 0, 0, 0);
    }
  }

  for (int p = 0; p <= cT; ++p) {
    bool active;
    short* hout;
    const short* h0p = P.h0hist + (size_t)p * 65536;       // h0(p-1); page 0 = zeros
    const short* ahp = h0p;
    if (layer == 0) {
      active = (p < cT);
      hout = P.h0hist + (size_t)(p + 1) * 65536;           // h0(p)
    } else {
      int t = p - 1;
      active = (t >= 0);
      int tt = t < 0 ? 0 : t;
      ahp = (t <= 0) ? P.zpage : (P.outs + (size_t)(tt - 1) * 65536);  // h1(t-1)
      hout = P.outs + (size_t)tt * 65536;
    }

    if (active) {
      f32x4 acc[2][2] = {};
      if (layer == 0) {
        // ---- single-shot async stage of the full h0(p-1) page (128 KB) ----
        #pragma unroll
        for (int j = 0; j < 32; ++j) {
          int s = tid + j * 256;
          gload16(h0p + s * 8, &sLDS[0][0] + s * 8);
        }
        __syncthreads();               // drains LDS-DMA (compiler emits vmcnt(0))
        if (kh == 1) {                 // Wh0 @ h0(p-1) from LDS
          const short* lb = &sLDS[0][0] + lhi * 512 + (mh * 32 + l15) * 8;
          #pragma unroll
          for (int kt = 0; kt < 32; ++kt) {
            bf16x8 a0 = *(const bf16x8*)(lb + kt * 2048);
            bf16x8 a1 = *(const bf16x8*)(lb + kt * 2048 + 128);
            acc[0][0] = __builtin_amdgcn_mfma_f32_16x16x32_bf16(a0, w[0][kt], acc[0][0], 0, 0, 0);
            acc[0][1] = __builtin_amdgcn_mfma_f32_16x16x32_bf16(a0, w[1][kt], acc[0][1], 0, 0, 0);
            acc[1][0] = __builtin_amdgcn_mfma_f32_16x16x32_bf16(a1, w[0][kt], acc[1][0], 0, 0, 0);
            acc[1][1] = __builtin_amdgcn_mfma_f32_16x16x32_bf16(a1, w[1][kt], acc[1][1], 0, 0, 0);
          }
        }
      } else {
        // ---- L1: double-buffered K-chunk pipeline (op0 = h0(t), op1 = h1(t-1)) ----
        #pragma unroll
        for (int j = 0; j < 8; ++j) {  // stage chunk 0
          int s = tid + j * 256;
          gload16(h0p + s * 8, &sLDS[0][0] + s * 8);
          gload16(ahp + s * 8, &sLDS[1][0] + s * 8);
        }
        __syncthreads();
        #pragma unroll
        for (int kc = 0; kc < 4; ++kc) {
          if (kc < 3) {                // prefetch chunk kc+1 into other buffer
            const short* g0 = h0p + (kc + 1) * 16384;
            const short* g1 = ahp + (kc + 1) * 16384;
            short* l0 = &sLDS[((kc + 1) & 1) * 2][0];
            short* l1 = &sLDS[((kc + 1) & 1) * 2 + 1][0];
            #pragma unroll
            for (int j = 0; j < 8; ++j) {
              int s = tid + j * 256;
              gload16(g0 + s * 8, l0 + s * 8);
              gload16(g1 + s * 8, l1 + s * 8);
            }
          }
          const short* lb = &sLDS[(kc & 1) * 2 + kh][0] + lhi * 512 + (mh * 32 + l15) * 8;
          #pragma unroll
          for (int kt = 0; kt < 8; ++kt) {
            bf16x8 a0 = *(const bf16x8*)(lb + kt * 2048);
            bf16x8 a1 = *(const bf16x8*)(lb + kt * 2048 + 128);
            acc[0][0] = __builtin_amdgcn_mfma_f32_16x16x32_bf16(a0, w[0][kc * 8 + kt], acc[0][0], 0, 0, 0);
            acc[0][1] = __builtin_amdgcn_mfma_f32_16x16x32_bf16(a0, w[1][kc * 8 + kt], acc[0][1], 0, 0, 0);
            acc[1][0] = __builtin_amdgcn_mfma_f32_16x16x32_bf16(a1, w[0][kc * 8 + kt], acc[1][0], 0, 0, 0);
            acc[1][1] = __builtin_amdgcn_mfma_f32_16x16x32_bf16(a1, w[1][kc * 8 + kt], acc[1][1], 0, 0, 0);
          }
          __syncthreads();             // chunk kc consumed; prefetch kc+1 drained
        }
      }

      bool useAccx = (layer == 0 && kh == 0);
      #pragma unroll
      for (int mi = 0; mi < 2; ++mi)
        #pragma unroll
        for (int ni = 0; ni < 2; ++ni)
          #pragma unroll
          for (int v = 0; v < 4; ++v)
            pLDS[wv][mi * 16 + lhi * 4 + v][ni * 16 + l15] =
                useAccx ? accx[mi][ni][v] : acc[mi][ni][v];
      __syncthreads();
      // fused x+h reduction + LSTM pointwise -> hLDS staging
      #pragma unroll
      for (int rep = 0; rep < 2; ++rep) {
        int e = tid + rep * 256;
        int b = e >> 3, hc = e & 7;
        int mq = (b >> 5) << 1;
        int mr = b & 31;
        float iv = pLDS[mq][mr][hc]      + pLDS[mq + 1][mr][hc]      + bLDS[hc];
        float fv = pLDS[mq][mr][8 + hc]  + pLDS[mq + 1][mr][8 + hc]  + bLDS[8 + hc];
        float gv = pLDS[mq][mr][16 + hc] + pLDS[mq + 1][mr][16 + hc] + bLDS[16 + hc];
        float ov = pLDS[mq][mr][24 + hc] + pLDS[mq + 1][mr][24 + hc] + bLDS[24 + hc];
        float cold = cLDS[e];
        float cn = sigf(fv) * cold + sigf(iv) * tanhf(gv);
        float hn = sigf(ov) * tanhf(cn);
        cLDS[e] = cn;
        hLDS[e] = f2b(hn);
      }
    }

    __syncthreads();   // hLDS complete (also joins !active blocks)
    const int tgt = p + 1;

    // ---- coalesced write-through h writeback (wave 0: 64 x 16B packets) ----
    if (wv == 0) {
      if (active) {
        short* houtS = hout + slice * 512;
        i32x4 hv = *(const i32x4*)&hLDS[lane * 8];
        asm volatile("global_store_dwordx4 %0, %1, off sc0 sc1"
                     :: "v"(houtS + lane * 8), "v"(hv) : "memory");
        asm volatile("s_waitcnt vmcnt(0)" ::: "memory");   // drained to coherent point
      }
      if (lane == 0)   // single-writer arrival word (plain relaxed store)
        __hip_atomic_store(&F[blk * FSTR], tgt, __ATOMIC_RELAXED, __HIP_MEMORY_SCOPE_AGENT);
    }

    // ---- useful-wait: L0 x-waves compute next phase's x-part during the sync ----
    if (layer == 0 && kh == 0 && tgt < cT) {
      #pragma unroll
      for (int mi = 0; mi < 2; ++mi)
        #pragma unroll
        for (int ni = 0; ni < 2; ++ni)
          accx[mi][ni] = (f32x4){0.f, 0.f, 0.f, 0.f};
      int xi = P.x[lane * cT + tgt];
      int v0 = __shfl(xi, mh * 32 + l15);
      int v1 = __shfl(xi, mh * 32 + l15 + 16);
      const short* b0 = P.embedb + (size_t)v0 * 1024 + lhi * 8;
      const short* b1 = P.embedb + (size_t)v1 * 1024 + lhi * 8;
      #pragma unroll
      for (int kt = 0; kt < 32; ++kt) {
        bf16x8 a0 = *(const bf16x8*)(b0 + kt * 32);
        bf16x8 a1 = *(const bf16x8*)(b1 + kt * 32);
        accx[0][0] = __builtin_amdgcn_mfma_f32_16x16x32_bf16(a0, w[0][kt], accx[0][0], 0, 0, 0);
        accx[0][1] = __builtin_amdgcn_mfma_f32_16x16x32_bf16(a0, w[1][kt], accx[0][1], 0, 0, 0);
        accx[1][0] = __builtin_amdgcn_mfma_f32_16x16x32_bf16(a1, w[0][kt], accx[1][0], 0, 0, 0);
        accx[1][1] = __builtin_amdgcn_mfma_f32_16x16x32_bf16(a1, w[1][kt], accx[1][1], 0, 0, 0);
      }
    }

    // ---- single-hop barrier: wave 1 sweeps arrival words directly ----
    if (wv == 1) {
      if (layer == 0) {
        bool done = false;
        while (!done) {
          int a0 = __hip_atomic_load(&F[lane * FSTR],        __ATOMIC_RELAXED, __HIP_MEMORY_SCOPE_AGENT);
          int a1 = __hip_atomic_load(&F[(lane + 64) * FSTR], __ATOMIC_RELAXED, __HIP_MEMORY_SCOPE_AGENT);
          done = __all(a0 >= tgt && a1 >= tgt);
          if (!done) __builtin_amdgcn_s_sleep(1);
        }
      } else {
        bool done = false;
        while (!done) {
          int a0 = __hip_atomic_load(&F[lane * FSTR],         __ATOMIC_RELAXED, __HIP_MEMORY_SCOPE_AGENT);
          int a1 = __hip_atomic_load(&F[(lane + 64) * FSTR],  __ATOMIC_RELAXED, __HIP_MEMORY_SCOPE_AGENT);
          int a2 = __hip_atomic_load(&F[(lane + 128) * FSTR], __ATOMIC_RELAXED, __HIP_MEMORY_SCOPE_AGENT);
          int a3 = __hip_atomic_load(&F[(lane + 192) * FSTR], __ATOMIC_RELAXED, __HIP_MEMORY_SCOPE_AGENT);
          done = __all(a0 >= tgt && a1 >= tgt && a2 >= tgt && a3 >= tgt);
          if (!done) __builtin_amdgcn_s_sleep(1);
        }
      }
    }
    __syncthreads();
  }
}

// ---------------- output projection (outs is slice-layout) ----------------
__launch_bounds__(256, 1)
__global__ void proj_kernel(const short* __restrict__ outs, const short* __restrict__ Woutb,
                            const float* __restrict__ bout, float* __restrict__ logits) {
  const int tid = threadIdx.x, lane = tid & 63, wv = tid >> 6;
  const int l15 = lane & 15, lhi = lane >> 4;
  const int t = blockIdx.x;
  const int row = wv * 16 + l15;
  const short* Abase = outs + (size_t)t * 65536;
  f32x4 acc[8] = {};
  for (int k = 0; k < 1024; k += 32) {
    bf16x8 af = *(const bf16x8*)(Abase + ((k >> 3) + lhi) * 512 + row * 8);
    #pragma unroll
    for (int nn = 0; nn < 8; ++nn) {
      bf16x8 bf = *(const bf16x8*)(Woutb + (size_t)(nn * 16 + l15) * 1024 + k + lhi * 8);
      acc[nn] = __builtin_amdgcn_mfma_f32_16x16x32_bf16(af, bf, acc[nn], 0, 0, 0);
    }
  }
  #pragma unroll
  for (int nn = 0; nn < 8; ++nn) {
    #pragma unroll
    for (int v = 0; v < 4; ++v) {
      int b = wv * 16 + lhi * 4 + v;
      int col = nn * 16 + l15;
      logits[(size_t)b * (cT * cV) + (size_t)t * cV + col] = acc[nn][v] + bout[col];
    }
  }
}

// ---------------- launch ----------------
extern "C" void kernel_launch(void* const* d_in, const int* in_sizes, int n_in,
                              void* d_out, int out_size, void* d_ws, size_t ws_size,
                              hipStream_t stream) {
  const int* x = (const int*)d_in[0];
  const float* embed = (const float*)d_in[1];
  const float* Wx = (const float*)d_in[2];
  const float* Wh = (const float*)d_in[3];
  const float* bias = (const float*)d_in[4];
  const float* Wout = (const float*)d_in[5];
  const float* bout = (const float*)d_in[6];
  float* logits = (float*)d_out;

  char* ws = (char*)d_ws;
  size_t off = 0;
  auto alloc = [&](size_t bytes) {
    char* p = ws + off;
    off += (bytes + 255) & ~(size_t)255;
    return p;
  };
  short* Woutb  = (short*)alloc((size_t)cV * cH * 2);
  short* embedb = (short*)alloc((size_t)cV * cD * 2);
  short* outs   = (short*)alloc((size_t)cT * 65536 * 2);
  short* h0hist = (short*)alloc((size_t)(cT + 1) * 65536 * 2);
  char* state0 = ws + off;
  short* zpage  = (short*)alloc((size_t)65536 * 2);
  int* flags    = (int*)alloc((size_t)NBLK * FSTR * sizeof(int));
  size_t state_bytes = (size_t)((ws + off) - state0);

  hipMemsetAsync(state0, 0, state_bytes, stream);
  hipMemsetAsync(h0hist, 0, (size_t)65536 * 2, stream);   // zero initial-h page

  int n8 = cV * cH / 8;
  cvt_bf16_kernel<<<(n8 + 255) / 256, 256, 0, stream>>>(Wout, Woutb, n8);
  cvt_bf16_kernel<<<(n8 + 255) / 256, 256, 0, stream>>>(embed, embedb, n8);

  RParams P{Wx, Wh, bias, x, embedb, h0hist, outs, zpage, flags};
  lstm_recurrent<<<dim3(NBLK), dim3(256), 0, stream>>>(P);

  proj_kernel<<<cT, 256, 0, stream>>>(outs, Woutb, bout, logits);
}

// Round 9
// 4351.876 us; speedup vs baseline: 5.3668x; 1.5795x over previous
//
#include <hip/hip_runtime.h>
#include <hip/hip_bf16.h>

constexpr int cV = 128, cD = 1024, cH = 1024, cB = 64, cT = 512;
constexpr int c4H = 4096;
constexpr int NBLK = 256;
constexpr int FSTR = 32;            // flag stride in ints (128 B per slot)
// h pages [64][1024] stored slice-wise: [128 col-octs][64 b][8]; page = 65536 shorts.
// addr(b,col) = (col>>3)*512 + b*8 + (col&7). Block (slice,bh) owns rows bh*32..+32 of slice.

typedef __attribute__((ext_vector_type(8))) short bf16x8;
typedef __attribute__((ext_vector_type(4))) float f32x4;
typedef __attribute__((ext_vector_type(4))) int i32x4;

__device__ __forceinline__ short f2b(float f) {
  __hip_bfloat16 h = __float2bfloat16(f);
  return __builtin_bit_cast(short, h);
}
__device__ __forceinline__ float sigf(float x) { return 1.0f / (1.0f + __expf(-x)); }

__device__ __forceinline__ void gload16(const short* g, short* l) {
  __builtin_amdgcn_global_load_lds(
      (const __attribute__((address_space(1))) void*)g,
      (__attribute__((address_space(3))) void*)l, 16, 0, 0);
}

// ---------------- f32 -> bf16 flat converter ----------------
__global__ void cvt_bf16_kernel(const float* __restrict__ src, short* __restrict__ dst, int n8) {
  int q = blockIdx.x * blockDim.x + threadIdx.x;
  if (q >= n8) return;
  const float4* s = (const float4*)src + (size_t)q * 2;
  float4 a = s[0], b = s[1];
  union { short s8[8]; int4 v; } u;
  u.s8[0] = f2b(a.x); u.s8[1] = f2b(a.y); u.s8[2] = f2b(a.z); u.s8[3] = f2b(a.w);
  u.s8[4] = f2b(b.x); u.s8[5] = f2b(b.y); u.s8[6] = f2b(b.z); u.s8[7] = f2b(b.w);
  *(int4*)(dst + (size_t)q * 8) = u.v;
}

// ---------------- fused 2-layer persistent recurrent kernel ----------------
struct RParams {
  const float* Wx;        // [L][4096][1024] f32
  const float* Wh;        // [L][4096][1024] f32
  const float* bias;      // [L][4096]
  const int*   x;         // [B][T]
  const short* embedb;    // [128][1024] bf16
  short* h0hist;          // [T+1] pages; page t+1 = h0(t), page 0 = zeros
  short* outs;            // [T] pages; page t = h1(t)
  const short* zpage;     // zeros page
  int* flags;             // [256*FSTR] per-block arrival words
};

__launch_bounds__(512, 1)
__global__ void lstm_recurrent(RParams P) {
  __shared__ __align__(16) short S0[32768];  // h0(p-1) bh-half: [128 oct][32 row][8]
  __shared__ __align__(16) short S1[32768];  // h1(p-2) bh-half
  __shared__ float pLDS[8][32][17];          // per-wave partial [32 batch x 16 cols]
  __shared__ float cLDS[512];                // cell state [layer][32 b][8 hc]
  __shared__ float bLDS[2][32];              // biases per layer's 32 gate-cols
  __shared__ short hLDS[512];                // staged h outputs [layer][32 b][8 hc]

  const int tid = threadIdx.x;
  const int lane = tid & 63, wv = tid >> 6;
  const int l15 = lane & 15, lhi = lane >> 4;
  const int op = wv & 3;               // 0=Wx0, 1=Wh0, 2=Wx1, 3=Wh1
  const int ns = wv >> 2;              // col half (16 gate-cols)
  const int blk = blockIdx.x;
  const int slice = blk & 127;
  const int bh = blk >> 7;             // batch half
  const int hc0 = slice * 8;
  int* F = P.flags;

  // ---- one-time: wave's 16x1024 weight slice -> registers ----
  bf16x8 w[32];
  {
    const float* Wsrc = ((op & 1) ? P.Wh : P.Wx) + (size_t)(op >> 1) * c4H * cD;
    int r = ns * 16 + l15;
    const float* base = Wsrc + (size_t)((r >> 3) * cH + hc0 + (r & 7)) * cD + lhi * 8;
    #pragma unroll
    for (int kt = 0; kt < 32; ++kt) {
      float4 a = *(const float4*)(base + kt * 32);
      float4 b = *(const float4*)(base + kt * 32 + 4);
      union { short s8[8]; bf16x8 v; } u;
      u.s8[0] = f2b(a.x); u.s8[1] = f2b(a.y); u.s8[2] = f2b(a.z); u.s8[3] = f2b(a.w);
      u.s8[4] = f2b(b.x); u.s8[5] = f2b(b.y); u.s8[6] = f2b(b.z); u.s8[7] = f2b(b.w);
      w[kt] = u.v;
    }
  }
  if (tid < 64) {
    int l = tid >> 5, r = tid & 31;
    bLDS[l][r] = P.bias[l * c4H + (r >> 3) * cH + hc0 + (r & 7)];
  }
  cLDS[tid] = 0.0f;
  __syncthreads();

  // ---- x-part precompute for slot 0 (op==0 waves) ----
  f32x4 accx[2] = {};
  if (op == 0) {
    int v0 = P.x[(bh * 32 + l15) * cT + 0];
    int v1 = P.x[(bh * 32 + 16 + l15) * cT + 0];
    const short* e0 = P.embedb + (size_t)v0 * 1024 + lhi * 8;
    const short* e1 = P.embedb + (size_t)v1 * 1024 + lhi * 8;
    #pragma unroll
    for (int kt = 0; kt < 32; ++kt) {
      bf16x8 a0 = *(const bf16x8*)(e0 + kt * 32);
      bf16x8 a1 = *(const bf16x8*)(e1 + kt * 32);
      accx[0] = __builtin_amdgcn_mfma_f32_16x16x32_bf16(a0, w[kt], accx[0], 0, 0, 0);
      accx[1] = __builtin_amdgcn_mfma_f32_16x16x32_bf16(a1, w[kt], accx[1], 0, 0, 0);
    }
  }

  for (int p = 0; p <= cT; ++p) {
    const bool l0act = (p < cT);        // produce h0(p)
    const bool l1act = (p >= 1);        // produce h1(p-1)
    const short* s0g = P.h0hist + (size_t)p * 65536;                     // h0(p-1)
    const short* s1g = (p >= 2) ? (P.outs + (size_t)(p - 2) * 65536) : P.zpage;  // h1(p-2)

    // ---- barrier poll: wave 7 sweeps all 256 arrival words for >= p ----
    if (wv == 7) {
      bool done = false;
      while (!done) {
        int a0 = __hip_atomic_load(&F[lane * FSTR],         __ATOMIC_RELAXED, __HIP_MEMORY_SCOPE_AGENT);
        int a1 = __hip_atomic_load(&F[(lane + 64) * FSTR],  __ATOMIC_RELAXED, __HIP_MEMORY_SCOPE_AGENT);
        int a2 = __hip_atomic_load(&F[(lane + 128) * FSTR], __ATOMIC_RELAXED, __HIP_MEMORY_SCOPE_AGENT);
        int a3 = __hip_atomic_load(&F[(lane + 192) * FSTR], __ATOMIC_RELAXED, __HIP_MEMORY_SCOPE_AGENT);
        done = __all(a0 >= p && a1 >= p && a2 >= p && a3 >= p);
        if (!done) __builtin_amdgcn_s_sleep(1);
      }
    }
    __syncthreads();

    // ---- stage both operand half-pages (64 KB each), interleaved DMA ----
    #pragma unroll
    for (int j = 0; j < 8; ++j) {
      int s = tid + j * 512;            // 16B segment 0..4095
      int oct = s >> 5, row = s & 31;
      const short* gsrc = s0g + oct * 512 + bh * 256 + row * 8;
      gload16(gsrc, S0 + s * 8);
      const short* gsrc1 = s1g + oct * 512 + bh * 256 + row * 8;
      gload16(gsrc1, S1 + s * 8);
    }
    __syncthreads();                    // drains LDS-DMA

    // ---- GEMM: each wave 64 MFMAs (op0 uses precomputed accx) ----
    f32x4 acc[2];
    if (op == 0) {
      acc[0] = accx[0]; acc[1] = accx[1];
    } else {
      acc[0] = (f32x4){0.f, 0.f, 0.f, 0.f};
      acc[1] = (f32x4){0.f, 0.f, 0.f, 0.f};
      const short* S = (op == 3) ? S1 : S0;
      const short* lb = S + lhi * 256 + l15 * 8;
      #pragma unroll
      for (int kt = 0; kt < 32; ++kt) {
        bf16x8 a0 = *(const bf16x8*)(lb + kt * 1024);
        bf16x8 a1 = *(const bf16x8*)(lb + kt * 1024 + 128);
        acc[0] = __builtin_amdgcn_mfma_f32_16x16x32_bf16(a0, w[kt], acc[0], 0, 0, 0);
        acc[1] = __builtin_amdgcn_mfma_f32_16x16x32_bf16(a1, w[kt], acc[1], 0, 0, 0);
      }
    }
    #pragma unroll
    for (int mi = 0; mi < 2; ++mi)
      #pragma unroll
      for (int v = 0; v < 4; ++v)
        pLDS[wv][mi * 16 + lhi * 4 + v][l15] = acc[mi][v];
    __syncthreads();

    // ---- fused x+h reduction + LSTM pointwise (one element per thread) ----
    {
      int l = tid >> 8, b = (tid >> 3) & 31, hc = tid & 7;
      bool act = l ? l1act : l0act;
      if (act) {
        float gt[4];
        #pragma unroll
        for (int g = 0; g < 4; ++g) {
          int r = g * 8 + hc;
          int wB = (r >> 4) * 4 + 2 * l;
          gt[g] = pLDS[wB][b][r & 15] + pLDS[wB + 1][b][r & 15] + bLDS[l][r];
        }
        float cold = cLDS[tid];
        float cn = sigf(gt[1]) * cold + sigf(gt[0]) * tanhf(gt[2]);
        float hn = sigf(gt[3]) * tanhf(cn);
        cLDS[tid] = cn;
        hLDS[tid] = f2b(hn);
      }
    }
    __syncthreads();

    // ---- coalesced write-through writeback: wave0 -> h0(p), wave4 -> h1(p-1) ----
    if (wv == 0) {
      if (l0act && lane < 32) {
        short* d = P.h0hist + (size_t)(p + 1) * 65536 + slice * 512 + bh * 256 + lane * 8;
        i32x4 hv = *(const i32x4*)&hLDS[lane * 8];
        asm volatile("global_store_dwordx4 %0, %1, off sc0 sc1" :: "v"(d), "v"(hv) : "memory");
      }
      asm volatile("s_waitcnt vmcnt(0)" ::: "memory");
    }
    if (wv == 4) {
      if (l1act && lane < 32) {
        short* d = P.outs + (size_t)(p - 1) * 65536 + slice * 512 + bh * 256 + lane * 8;
        i32x4 hv = *(const i32x4*)&hLDS[256 + lane * 8];
        asm volatile("global_store_dwordx4 %0, %1, off sc0 sc1" :: "v"(d), "v"(hv) : "memory");
      }
      asm volatile("s_waitcnt vmcnt(0)" ::: "memory");
    }
    __syncthreads();                    // both writers drained
    if (tid == 0)
      __hip_atomic_store(&F[blk * FSTR], p + 1, __ATOMIC_RELAXED, __HIP_MEMORY_SCOPE_AGENT);

    // ---- useful-wait: op0 waves precompute next slot's x-part ----
    if (op == 0) {
      accx[0] = (f32x4){0.f, 0.f, 0.f, 0.f};
      accx[1] = (f32x4){0.f, 0.f, 0.f, 0.f};
      if (p + 1 < cT) {
        int t = p + 1;
        int v0 = P.x[(bh * 32 + l15) * cT + t];
        int v1 = P.x[(bh * 32 + 16 + l15) * cT + t];
        const short* e0 = P.embedb + (size_t)v0 * 1024 + lhi * 8;
        const short* e1 = P.embedb + (size_t)v1 * 1024 + lhi * 8;
        #pragma unroll
        for (int kt = 0; kt < 32; ++kt) {
          bf16x8 a0 = *(const bf16x8*)(e0 + kt * 32);
          bf16x8 a1 = *(const bf16x8*)(e1 + kt * 32);
          accx[0] = __builtin_amdgcn_mfma_f32_16x16x32_bf16(a0, w[kt], accx[0], 0, 0, 0);
          accx[1] = __builtin_amdgcn_mfma_f32_16x16x32_bf16(a1, w[kt], accx[1], 0, 0, 0);
        }
      }
    }
  }
}

// ---------------- output projection (outs is slice-layout) ----------------
__launch_bounds__(256, 1)
__global__ void proj_kernel(const short* __restrict__ outs, const short* __restrict__ Woutb,
                            const float* __restrict__ bout, float* __restrict__ logits) {
  const int tid = threadIdx.x, lane = tid & 63, wv = tid >> 6;
  const int l15 = lane & 15, lhi = lane >> 4;
  const int t = blockIdx.x;
  const int row = wv * 16 + l15;
  const short* Abase = outs + (size_t)t * 65536;
  f32x4 acc[8] = {};
  for (int k = 0; k < 1024; k += 32) {
    bf16x8 af = *(const bf16x8*)(Abase + ((k >> 3) + lhi) * 512 + row * 8);
    #pragma unroll
    for (int nn = 0; nn < 8; ++nn) {
      bf16x8 bf = *(const bf16x8*)(Woutb + (size_t)(nn * 16 + l15) * 1024 + k + lhi * 8);
      acc[nn] = __builtin_amdgcn_mfma_f32_16x16x32_bf16(af, bf, acc[nn], 0, 0, 0);
    }
  }
  #pragma unroll
  for (int nn = 0; nn < 8; ++nn) {
    #pragma unroll
    for (int v = 0; v < 4; ++v) {
      int b = wv * 16 + lhi * 4 + v;
      int col = nn * 16 + l15;
      logits[(size_t)b * (cT * cV) + (size_t)t * cV + col] = acc[nn][v] + bout[col];
    }
  }
}

// ---------------- launch ----------------
extern "C" void kernel_launch(void* const* d_in, const int* in_sizes, int n_in,
                              void* d_out, int out_size, void* d_ws, size_t ws_size,
                              hipStream_t stream) {
  const int* x = (const int*)d_in[0];
  const float* embed = (const float*)d_in[1];
  const float* Wx = (const float*)d_in[2];
  const float* Wh = (const float*)d_in[3];
  const float* bias = (const float*)d_in[4];
  const float* Wout = (const float*)d_in[5];
  const float* bout = (const float*)d_in[6];
  float* logits = (float*)d_out;

  char* ws = (char*)d_ws;
  size_t off = 0;
  auto alloc = [&](size_t bytes) {
    char* p = ws + off;
    off += (bytes + 255) & ~(size_t)255;
    return p;
  };
  short* Woutb  = (short*)alloc((size_t)cV * cH * 2);
  short* embedb = (short*)alloc((size_t)cV * cD * 2);
  short* outs   = (short*)alloc((size_t)cT * 65536 * 2);
  short* h0hist = (short*)alloc((size_t)(cT + 1) * 65536 * 2);
  char* state0 = ws + off;
  short* zpage  = (short*)alloc((size_t)65536 * 2);
  int* flags    = (int*)alloc((size_t)NBLK * FSTR * sizeof(int));
  size_t state_bytes = (size_t)((ws + off) - state0);

  hipMemsetAsync(state0, 0, state_bytes, stream);
  hipMemsetAsync(h0hist, 0, (size_t)65536 * 2, stream);   // zero initial-h page

  int n8 = cV * cH / 8;
  cvt_bf16_kernel<<<(n8 + 255) / 256, 256, 0, stream>>>(Wout, Woutb, n8);
  cvt_bf16_kernel<<<(n8 + 255) / 256, 256, 0, stream>>>(embed, embedb, n8);

  RParams P{Wx, Wh, bias, x, embedb, h0hist, outs, zpage, flags};
  lstm_recurrent<<<dim3(NBLK), dim3(512), 0, stream>>>(P);

  proj_kernel<<<cT, 256, 0, stream>>>(outs, Woutb, bout, logits);
}

// Round 12
// 4226.323 us; speedup vs baseline: 5.5262x; 1.0297x over previous
//
#include <hip/hip_runtime.h>
#include <hip/hip_bf16.h>

constexpr int cV = 128, cD = 1024, cH = 1024, cB = 64, cT = 512;
constexpr int c4H = 4096;
constexpr int NBLK = 256;
constexpr int FSTR = 32;            // flag stride in ints (128 B per slot)
// h pages [64][1024] stored slice-wise: [128 oct][64 b][8]; page = 65536 shorts.
// addr(b,col) = (col>>3)*512 + b*8 + (col&7). Block (slice,bh) owns rows bh*32..+32, cols 8*slice..+8.

typedef __attribute__((ext_vector_type(8))) short bf16x8;
typedef __attribute__((ext_vector_type(4))) float f32x4;
typedef __attribute__((ext_vector_type(4))) int i32x4;

__device__ __forceinline__ short f2b(float f) {
  __hip_bfloat16 h = __float2bfloat16(f);
  return __builtin_bit_cast(short, h);
}
__device__ __forceinline__ float sigf(float x) { return 1.0f / (1.0f + __expf(-x)); }

__device__ __forceinline__ void gload16(const short* g, short* l) {
  __builtin_amdgcn_global_load_lds(
      (const __attribute__((address_space(1))) void*)g,
      (__attribute__((address_space(3))) void*)l, 16, 0, 0);
}

// ---------------- f32 -> bf16 flat converter ----------------
__global__ void cvt_bf16_kernel(const float* __restrict__ src, short* __restrict__ dst, int n8) {
  int q = blockIdx.x * blockDim.x + threadIdx.x;
  if (q >= n8) return;
  const float4* s = (const float4*)src + (size_t)q * 2;
  float4 a = s[0], b = s[1];
  union { short s8[8]; int4 v; } u;
  u.s8[0] = f2b(a.x); u.s8[1] = f2b(a.y); u.s8[2] = f2b(a.z); u.s8[3] = f2b(a.w);
  u.s8[4] = f2b(b.x); u.s8[5] = f2b(b.y); u.s8[6] = f2b(b.z); u.s8[7] = f2b(b.w);
  *(int4*)(dst + (size_t)q * 8) = u.v;
}

// ---------------- fused 2-layer persistent recurrent kernel ----------------
struct RParams {
  const float* Wx;        // [L][4096][1024] f32
  const float* Wh;        // [L][4096][1024] f32
  const float* bias;      // [L][4096]
  const int*   x;         // [B][T]
  const short* embedb;    // [128][1024] bf16
  short* h0hist;          // [T+1] pages; page t+1 = h0(t), page 0 = zeros
  short* outs;            // [T] pages; page t = h1(t)
  const short* zpage;     // zeros page
  int* flags;             // [256*FSTR] per-block arrival words
};

__launch_bounds__(512, 1)
__global__ void lstm_recurrent(RParams P) {
  __shared__ __align__(16) short S0[32768];  // h0(p-1) bh-half: [128 oct][32 row][8]
  __shared__ __align__(16) short S1[32768];  // h1(p-2) bh-half
  __shared__ float pLDS[8][32][17];          // per-wave partial [32 batch x 16 cols]
  __shared__ float cLDS[512];                // cell state [layer][32 b][8 hc]
  __shared__ float bLDS[2][32];              // biases per layer's 32 gate-cols
  __shared__ short hLDS[512];                // staged h outputs [layer][32 b][8 hc]

  const int tid = threadIdx.x;
  const int lane = tid & 63, wv = tid >> 6;
  const int l15 = lane & 15, lhi = lane >> 4;
  const int op = wv & 3;               // 0=Wx0, 1=Wh0, 2=Wx1, 3=Wh1
  const int ns = wv >> 2;              // col half (16 gate-cols)
  const int blk = blockIdx.x;
  const int slice = blk & 127;
  const int bh = blk >> 7;             // batch half (independent recurrence domain)
  const int hc0 = slice * 8;
  int* F = P.flags;
  const int fbase = bh * 128;          // this domain's 128 flags

  // ---- one-time: wave's 16x1024 weight slice -> registers ----
  bf16x8 w[32];
  {
    const float* Wsrc = ((op & 1) ? P.Wh : P.Wx) + (size_t)(op >> 1) * c4H * cD;
    int r = ns * 16 + l15;
    const float* base = Wsrc + (size_t)((r >> 3) * cH + hc0 + (r & 7)) * cD + lhi * 8;
    #pragma unroll
    for (int kt = 0; kt < 32; ++kt) {
      float4 a = *(const float4*)(base + kt * 32);
      float4 b = *(const float4*)(base + kt * 32 + 4);
      union { short s8[8]; bf16x8 v; } u;
      u.s8[0] = f2b(a.x); u.s8[1] = f2b(a.y); u.s8[2] = f2b(a.z); u.s8[3] = f2b(a.w);
      u.s8[4] = f2b(b.x); u.s8[5] = f2b(b.y); u.s8[6] = f2b(b.z); u.s8[7] = f2b(b.w);
      w[kt] = u.v;
    }
  }
  if (tid < 64) {
    int l = tid >> 5, r = tid & 31;
    bLDS[l][r] = P.bias[l * c4H + (r >> 3) * cH + hc0 + (r & 7)];
  }
  cLDS[tid] = 0.0f;
  __syncthreads();

  // ---- x-part precompute for slot 0 (op==0 waves) ----
  f32x4 accx[2] = {};
  if (op == 0) {
    int v0 = P.x[(bh * 32 + l15) * cT + 0];
    int v1 = P.x[(bh * 32 + 16 + l15) * cT + 0];
    const short* e0 = P.embedb + (size_t)v0 * 1024 + lhi * 8;
    const short* e1 = P.embedb + (size_t)v1 * 1024 + lhi * 8;
    #pragma unroll
    for (int kt = 0; kt < 32; ++kt) {
      bf16x8 a0 = *(const bf16x8*)(e0 + kt * 32);
      bf16x8 a1 = *(const bf16x8*)(e1 + kt * 32);
      accx[0] = __builtin_amdgcn_mfma_f32_16x16x32_bf16(a0, w[kt], accx[0], 0, 0, 0);
      accx[1] = __builtin_amdgcn_mfma_f32_16x16x32_bf16(a1, w[kt], accx[1], 0, 0, 0);
    }
  }

  for (int p = 0; p <= cT; ++p) {
    const bool l0act = (p < cT);        // produce h0(p)
    const bool l1act = (p >= 1);        // produce h1(p-1)
    const short* s0g = P.h0hist + (size_t)p * 65536;                     // h0(p-1)
    const short* s1g = (p >= 2) ? (P.outs + (size_t)(p - 2) * 65536) : P.zpage;  // h1(p-2)

    // ---- barrier poll: wave 7 sweeps OWN DOMAIN's 128 arrival words for >= p ----
    if (wv == 7) {
      bool done = false;
      while (!done) {
        int a0 = __hip_atomic_load(&F[(fbase + lane) * FSTR],
                                   __ATOMIC_RELAXED, __HIP_MEMORY_SCOPE_AGENT);
        int a1 = __hip_atomic_load(&F[(fbase + 64 + lane) * FSTR],
                                   __ATOMIC_RELAXED, __HIP_MEMORY_SCOPE_AGENT);
        done = __all(a0 >= p && a1 >= p);
        if (!done) __builtin_amdgcn_s_sleep(1);
      }
    }
    __syncthreads();   // sync1: domain producers published

    // ---- stage both operand half-pages (64 KB each), all threads ----
    #pragma unroll
    for (int j = 0; j < 8; ++j) {
      int s = tid + j * 512;            // 16B segment 0..4095
      int oct = s >> 5, row = s & 31;
      const short* gsrc = s0g + oct * 512 + bh * 256 + row * 8;
      gload16(gsrc, S0 + s * 8);
      const short* gsrc1 = s1g + oct * 512 + bh * 256 + row * 8;
      gload16(gsrc1, S1 + s * 8);
    }
    __syncthreads();   // sync2: LDS-DMA drained

    // ---- GEMM(p): 8 waves x 64 MFMAs (op0 uses precomputed accx) ----
    f32x4 acc[2];
    if (op == 0) {
      acc[0] = accx[0]; acc[1] = accx[1];
    } else {
      acc[0] = (f32x4){0.f, 0.f, 0.f, 0.f};
      acc[1] = (f32x4){0.f, 0.f, 0.f, 0.f};
      const short* S = (op == 3) ? S1 : S0;
      const short* lb = S + lhi * 256 + l15 * 8;
      #pragma unroll
      for (int kt = 0; kt < 32; ++kt) {
        bf16x8 a0 = *(const bf16x8*)(lb + kt * 1024);
        bf16x8 a1 = *(const bf16x8*)(lb + kt * 1024 + 128);
        acc[0] = __builtin_amdgcn_mfma_f32_16x16x32_bf16(a0, w[kt], acc[0], 0, 0, 0);
        acc[1] = __builtin_amdgcn_mfma_f32_16x16x32_bf16(a1, w[kt], acc[1], 0, 0, 0);
      }
    }
    #pragma unroll
    for (int mi = 0; mi < 2; ++mi)
      #pragma unroll
      for (int v = 0; v < 4; ++v)
        pLDS[wv][mi * 16 + lhi * 4 + v][l15] = acc[mi][v];
    __syncthreads();   // sync3: pLDS ready

    // ---- fused x+h reduction + LSTM pointwise (one element per thread) ----
    {
      int l = tid >> 8, b = (tid >> 3) & 31, hc = tid & 7;
      bool act = l ? l1act : l0act;
      if (act) {
        float gt[4];
        #pragma unroll
        for (int g = 0; g < 4; ++g) {
          int r = g * 8 + hc;
          int wB = (r >> 4) * 4 + 2 * l;
          gt[g] = pLDS[wB][b][r & 15] + pLDS[wB + 1][b][r & 15] + bLDS[l][r];
        }
        float cold = cLDS[tid];
        float cn = sigf(gt[1]) * cold + sigf(gt[0]) * tanhf(gt[2]);
        float hn = sigf(gt[3]) * tanhf(cn);
        cLDS[tid] = cn;
        hLDS[tid] = f2b(hn);
      }
    }
    __syncthreads();   // sync4: hLDS complete

    // ---- single-wave writeback (wave0: lanes 0-31 -> h0(p), 32-63 -> h1(p-1)) + flag ----
    if (wv == 0) {
      bool doStore = (lane < 32) ? l0act : l1act;
      if (doStore) {
        short* d = (lane < 32)
            ? (P.h0hist + (size_t)(p + 1) * 65536 + slice * 512 + bh * 256 + (lane & 31) * 8)
            : (P.outs   + (size_t)(p - 1) * 65536 + slice * 512 + bh * 256 + (lane & 31) * 8);
        i32x4 hv = *(const i32x4*)&hLDS[lane * 8];
        asm volatile("global_store_dwordx4 %0, %1, off sc0 sc1" :: "v"(d), "v"(hv) : "memory");
      }
      asm volatile("s_waitcnt vmcnt(0)" ::: "memory");   // both pages at coherent point
      if (lane == 0)
        __hip_atomic_store(&F[blk * FSTR], p + 1, __ATOMIC_RELAXED, __HIP_MEMORY_SCOPE_AGENT);
    }

    // ---- useful-wait: op0 waves precompute next slot's x-part ----
    if (op == 0) {
      accx[0] = (f32x4){0.f, 0.f, 0.f, 0.f};
      accx[1] = (f32x4){0.f, 0.f, 0.f, 0.f};
      if (p + 1 < cT) {
        int t = p + 1;
        int v0 = P.x[(bh * 32 + l15) * cT + t];
        int v1 = P.x[(bh * 32 + 16 + l15) * cT + t];
        const short* e0 = P.embedb + (size_t)v0 * 1024 + lhi * 8;
        const short* e1 = P.embedb + (size_t)v1 * 1024 + lhi * 8;
        #pragma unroll
        for (int kt = 0; kt < 32; ++kt) {
          bf16x8 a0 = *(const bf16x8*)(e0 + kt * 32);
          bf16x8 a1 = *(const bf16x8*)(e1 + kt * 32);
          accx[0] = __builtin_amdgcn_mfma_f32_16x16x32_bf16(a0, w[kt], accx[0], 0, 0, 0);
          accx[1] = __builtin_amdgcn_mfma_f32_16x16x32_bf16(a1, w[kt], accx[1], 0, 0, 0);
        }
      }
    }
  }
}

// ---------------- output projection (outs is slice-layout) ----------------
__launch_bounds__(256, 1)
__global__ void proj_kernel(const short* __restrict__ outs, const short* __restrict__ Woutb,
                            const float* __restrict__ bout, float* __restrict__ logits) {
  const int tid = threadIdx.x, lane = tid & 63, wv = tid >> 6;
  const int l15 = lane & 15, lhi = lane >> 4;
  const int t = blockIdx.x;
  const int row = wv * 16 + l15;
  const short* Abase = outs + (size_t)t * 65536;
  f32x4 acc[8] = {};
  for (int k = 0; k < 1024; k += 32) {
    bf16x8 af = *(const bf16x8*)(Abase + ((k >> 3) + lhi) * 512 + row * 8);
    #pragma unroll
    for (int nn = 0; nn < 8; ++nn) {
      bf16x8 bf = *(const bf16x8*)(Woutb + (size_t)(nn * 16 + l15) * 1024 + k + lhi * 8);
      acc[nn] = __builtin_amdgcn_mfma_f32_16x16x32_bf16(af, bf, acc[nn], 0, 0, 0);
    }
  }
  #pragma unroll
  for (int nn = 0; nn < 8; ++nn) {
    #pragma unroll
    for (int v = 0; v < 4; ++v) {
      int b = wv * 16 + lhi * 4 + v;
      int col = nn * 16 + l15;
      logits[(size_t)b * (cT * cV) + (size_t)t * cV + col] = acc[nn][v] + bout[col];
    }
  }
}

// ---------------- launch ----------------
extern "C" void kernel_launch(void* const* d_in, const int* in_sizes, int n_in,
                              void* d_out, int out_size, void* d_ws, size_t ws_size,
                              hipStream_t stream) {
  const int* x = (const int*)d_in[0];
  const float* embed = (const float*)d_in[1];
  const float* Wx = (const float*)d_in[2];
  const float* Wh = (const float*)d_in[3];
  const float* bias = (const float*)d_in[4];
  const float* Wout = (const float*)d_in[5];
  const float* bout = (const float*)d_in[6];
  float* logits = (float*)d_out;

  char* ws = (char*)d_ws;
  size_t off = 0;
  auto alloc = [&](size_t bytes) {
    char* p = ws + off;
    off += (bytes + 255) & ~(size_t)255;
    return p;
  };
  short* Woutb  = (short*)alloc((size_t)cV * cH * 2);
  short* embedb = (short*)alloc((size_t)cV * cD * 2);
  short* outs   = (short*)alloc((size_t)cT * 65536 * 2);
  short* h0hist = (short*)alloc((size_t)(cT + 1) * 65536 * 2);
  char* state0 = ws + off;
  short* zpage  = (short*)alloc((size_t)65536 * 2);
  int* flags    = (int*)alloc((size_t)NBLK * FSTR * sizeof(int));
  size_t state_bytes = (size_t)((ws + off) - state0);

  hipMemsetAsync(state0, 0, state_bytes, stream);
  hipMemsetAsync(h0hist, 0, (size_t)65536 * 2, stream);   // zero initial-h page

  int n8 = cV * cH / 8;
  cvt_bf16_kernel<<<(n8 + 255) / 256, 256, 0, stream>>>(Wout, Woutb, n8);
  cvt_bf16_kernel<<<(n8 + 255) / 256, 256, 0, stream>>>(embed, embedb, n8);

  RParams P{Wx, Wh, bias, x, embedb, h0hist, outs, zpage, flags};
  lstm_recurrent<<<dim3(NBLK), dim3(512), 0, stream>>>(P);

  proj_kernel<<<cT, 256, 0, stream>>>(outs, Woutb, bout, logits);
}

// Round 13
// 4220.109 us; speedup vs baseline: 5.5343x; 1.0015x over previous
//
#include <hip/hip_runtime.h>
#include <hip/hip_bf16.h>

constexpr int cV = 128, cD = 1024, cH = 1024, cB = 64, cT = 512;
constexpr int c4H = 4096;
constexpr int NBLK = 256;
constexpr int FSTR = 32;            // flag stride in ints (128 B per slot)
// h pages [64][1024] stored slice-wise: [128 oct][64 b][8]; page = 65536 shorts.
// addr(b,col) = (col>>3)*512 + b*8 + (col&7). Block (slice,bh) owns rows bh*32..+32, cols 8*slice..+8.

typedef __attribute__((ext_vector_type(8))) short bf16x8;
typedef __attribute__((ext_vector_type(4))) float f32x4;
typedef __attribute__((ext_vector_type(4))) int i32x4;

__device__ __forceinline__ short f2b(float f) {
  __hip_bfloat16 h = __float2bfloat16(f);
  return __builtin_bit_cast(short, h);
}
__device__ __forceinline__ float sigf(float x) { return 1.0f / (1.0f + __expf(-x)); }

__device__ __forceinline__ void gload16(const short* g, short* l) {
  __builtin_amdgcn_global_load_lds(
      (const __attribute__((address_space(1))) void*)g,
      (__attribute__((address_space(3))) void*)l, 16, 0, 0);
}

// ---------------- f32 -> bf16 flat converter ----------------
__global__ void cvt_bf16_kernel(const float* __restrict__ src, short* __restrict__ dst, int n8) {
  int q = blockIdx.x * blockDim.x + threadIdx.x;
  if (q >= n8) return;
  const float4* s = (const float4*)src + (size_t)q * 2;
  float4 a = s[0], b = s[1];
  union { short s8[8]; int4 v; } u;
  u.s8[0] = f2b(a.x); u.s8[1] = f2b(a.y); u.s8[2] = f2b(a.z); u.s8[3] = f2b(a.w);
  u.s8[4] = f2b(b.x); u.s8[5] = f2b(b.y); u.s8[6] = f2b(b.z); u.s8[7] = f2b(b.w);
  *(int4*)(dst + (size_t)q * 8) = u.v;
}

// ---------------- fused 2-layer persistent recurrent kernel ----------------
struct RParams {
  const float* Wx;        // [L][4096][1024] f32
  const float* Wh;        // [L][4096][1024] f32
  const float* bias;      // [L][4096]
  const int*   x;         // [B][T]
  const short* embedb;    // [128][1024] bf16
  short* h0hist;          // [T+1] pages; page t+1 = h0(t), page 0 = zeros
  short* outs;            // [T] pages; page t = h1(t)
  const short* zpage;     // zeros page
  int* flags;             // [256*FSTR] per-block arrival words
};

__launch_bounds__(512, 1)
__global__ void lstm_recurrent(RParams P) {
  __shared__ __align__(16) short S0[32768];  // h0(p-1) bh-half: [128 oct][32 row][8]
  __shared__ __align__(16) short S1[32768];  // h1(p-2) bh-half
  __shared__ float pLDS[8][32][17];          // per-wave partial [32 batch x 16 cols]
  __shared__ float cLDS[512];                // cell state [layer][32 b][8 hc]
  __shared__ float bLDS[2][32];              // biases per layer's 32 gate-cols
  __shared__ short hLDS[512];                // staged h outputs [layer][32 b][8 hc]

  const int tid = threadIdx.x;
  const int lane = tid & 63, wv = tid >> 6;
  const int l15 = lane & 15, lhi = lane >> 4;
  const int op = wv & 3;               // 0=Wx0, 1=Wh0, 2=Wx1, 3=Wh1
  const int ns = wv >> 2;              // col half (16 gate-cols)
  const int blk = blockIdx.x;
  const int slice = blk & 127;
  const int bh = blk >> 7;             // batch half (independent recurrence domain)
  const int hc0 = slice * 8;
  int* F = P.flags;
  const int fbase = bh * 128;          // this domain's 128 flags

  // ---- one-time: wave's 16x1024 weight slice -> registers ----
  bf16x8 w[32];
  {
    const float* Wsrc = ((op & 1) ? P.Wh : P.Wx) + (size_t)(op >> 1) * c4H * cD;
    int r = ns * 16 + l15;
    const float* base = Wsrc + (size_t)((r >> 3) * cH + hc0 + (r & 7)) * cD + lhi * 8;
    #pragma unroll
    for (int kt = 0; kt < 32; ++kt) {
      float4 a = *(const float4*)(base + kt * 32);
      float4 b = *(const float4*)(base + kt * 32 + 4);
      union { short s8[8]; bf16x8 v; } u;
      u.s8[0] = f2b(a.x); u.s8[1] = f2b(a.y); u.s8[2] = f2b(a.z); u.s8[3] = f2b(a.w);
      u.s8[4] = f2b(b.x); u.s8[5] = f2b(b.y); u.s8[6] = f2b(b.z); u.s8[7] = f2b(b.w);
      w[kt] = u.v;
    }
  }
  if (tid < 64) {
    int l = tid >> 5, r = tid & 31;
    bLDS[l][r] = P.bias[l * c4H + (r >> 3) * cH + hc0 + (r & 7)];
  }
  cLDS[tid] = 0.0f;
  __syncthreads();

  // ---- x-part precompute for slot 0 (op==0 waves) ----
  f32x4 accx[2] = {};
  if (op == 0) {
    int v0 = P.x[(bh * 32 + l15) * cT + 0];
    int v1 = P.x[(bh * 32 + 16 + l15) * cT + 0];
    const short* e0 = P.embedb + (size_t)v0 * 1024 + lhi * 8;
    const short* e1 = P.embedb + (size_t)v1 * 1024 + lhi * 8;
    #pragma unroll
    for (int kt = 0; kt < 32; ++kt) {
      bf16x8 a0 = *(const bf16x8*)(e0 + kt * 32);
      bf16x8 a1 = *(const bf16x8*)(e1 + kt * 32);
      accx[0] = __builtin_amdgcn_mfma_f32_16x16x32_bf16(a0, w[kt], accx[0], 0, 0, 0);
      accx[1] = __builtin_amdgcn_mfma_f32_16x16x32_bf16(a1, w[kt], accx[1], 0, 0, 0);
    }
  }

  for (int p = 0; p <= cT; ++p) {
    const bool l0act = (p < cT);        // produce h0(p)
    const bool l1act = (p >= 1);        // produce h1(p-1)
    const short* s0g = P.h0hist + (size_t)p * 65536;                     // h0(p-1)
    const short* s1g = (p >= 2) ? (P.outs + (size_t)(p - 2) * 65536) : P.zpage;  // h1(p-2)

    // ---- fused poll+stage: waves 6,7 chunk-DMA each producer pair as it arrives ----
    // chunk c (0..63) = octs {2c, 2c+1}, producers = domain blocks {2c, 2c+1}.
    // wave7 stages S0 (h0(p-1)), wave6 stages S1 (h1(p-2)).
    // LDS dest per inner iteration: uniform base (c*1024B) + lane*16B  -> DMA-legal.
    if (wv >= 6) {
      const int* fa = &F[(fbase + 2 * lane) * FSTR];
      const int* fb = &F[(fbase + 2 * lane + 1) * FSTR];
      const short* gsrc = (wv == 7) ? s0g : s1g;
      short* ldst = (wv == 7) ? S0 : S1;
      unsigned long long staged = 0ull;
      while (staged != ~0ull) {
        int va = __hip_atomic_load(fa, __ATOMIC_RELAXED, __HIP_MEMORY_SCOPE_AGENT);
        int vb = __hip_atomic_load(fb, __ATOMIC_RELAXED, __HIP_MEMORY_SCOPE_AGENT);
        unsigned long long m = __ballot(va >= p && vb >= p) & ~staged;
        if (!m) { __builtin_amdgcn_s_sleep(1); continue; }
        staged |= m;
        while (m) {
          int c = __builtin_ctzll(m);
          m &= m - 1;
          int oct = 2 * c + (lane >> 5);
          int row = lane & 31;
          gload16(gsrc + oct * 512 + bh * 256 + row * 8, ldst + (c * 64 + lane) * 8);
        }
      }
      asm volatile("s_waitcnt vmcnt(0)" ::: "memory");   // all chunk DMA landed
    }
    __syncthreads();   // sync2: S0/S1 staged (and all producers >= p)

    // ---- GEMM(p): 8 waves x 64 MFMAs (op0 uses precomputed accx) ----
    f32x4 acc[2];
    if (op == 0) {
      acc[0] = accx[0]; acc[1] = accx[1];
    } else {
      acc[0] = (f32x4){0.f, 0.f, 0.f, 0.f};
      acc[1] = (f32x4){0.f, 0.f, 0.f, 0.f};
      const short* S = (op == 3) ? S1 : S0;
      const short* lb = S + lhi * 256 + l15 * 8;
      #pragma unroll
      for (int kt = 0; kt < 32; ++kt) {
        bf16x8 a0 = *(const bf16x8*)(lb + kt * 1024);
        bf16x8 a1 = *(const bf16x8*)(lb + kt * 1024 + 128);
        acc[0] = __builtin_amdgcn_mfma_f32_16x16x32_bf16(a0, w[kt], acc[0], 0, 0, 0);
        acc[1] = __builtin_amdgcn_mfma_f32_16x16x32_bf16(a1, w[kt], acc[1], 0, 0, 0);
      }
    }
    #pragma unroll
    for (int mi = 0; mi < 2; ++mi)
      #pragma unroll
      for (int v = 0; v < 4; ++v)
        pLDS[wv][mi * 16 + lhi * 4 + v][l15] = acc[mi][v];
    __syncthreads();   // sync3: pLDS ready

    // ---- fused x+h reduction + LSTM pointwise (one element per thread) ----
    {
      int l = tid >> 8, b = (tid >> 3) & 31, hc = tid & 7;
      bool act = l ? l1act : l0act;
      if (act) {
        float gt[4];
        #pragma unroll
        for (int g = 0; g < 4; ++g) {
          int r = g * 8 + hc;
          int wB = (r >> 4) * 4 + 2 * l;
          gt[g] = pLDS[wB][b][r & 15] + pLDS[wB + 1][b][r & 15] + bLDS[l][r];
        }
        float cold = cLDS[tid];
        float cn = sigf(gt[1]) * cold + sigf(gt[0]) * tanhf(gt[2]);
        float hn = sigf(gt[3]) * tanhf(cn);
        cLDS[tid] = cn;
        hLDS[tid] = f2b(hn);
      }
    }
    __syncthreads();   // sync4: hLDS complete

    // ---- single-wave writeback (wave0: lanes 0-31 -> h0(p), 32-63 -> h1(p-1)) + flag ----
    if (wv == 0) {
      bool doStore = (lane < 32) ? l0act : l1act;
      if (doStore) {
        short* d = (lane < 32)
            ? (P.h0hist + (size_t)(p + 1) * 65536 + slice * 512 + bh * 256 + (lane & 31) * 8)
            : (P.outs   + (size_t)(p - 1) * 65536 + slice * 512 + bh * 256 + (lane & 31) * 8);
        i32x4 hv = *(const i32x4*)&hLDS[lane * 8];
        asm volatile("global_store_dwordx4 %0, %1, off sc0 sc1" :: "v"(d), "v"(hv) : "memory");
      }
      asm volatile("s_waitcnt vmcnt(0)" ::: "memory");   // both pages at coherent point
      if (lane == 0)
        __hip_atomic_store(&F[blk * FSTR], p + 1, __ATOMIC_RELAXED, __HIP_MEMORY_SCOPE_AGENT);
    }

    // ---- useful-wait: op0 waves precompute next slot's x-part ----
    if (op == 0) {
      accx[0] = (f32x4){0.f, 0.f, 0.f, 0.f};
      accx[1] = (f32x4){0.f, 0.f, 0.f, 0.f};
      if (p + 1 < cT) {
        int t = p + 1;
        int v0 = P.x[(bh * 32 + l15) * cT + t];
        int v1 = P.x[(bh * 32 + 16 + l15) * cT + t];
        const short* e0 = P.embedb + (size_t)v0 * 1024 + lhi * 8;
        const short* e1 = P.embedb + (size_t)v1 * 1024 + lhi * 8;
        #pragma unroll
        for (int kt = 0; kt < 32; ++kt) {
          bf16x8 a0 = *(const bf16x8*)(e0 + kt * 32);
          bf16x8 a1 = *(const bf16x8*)(e1 + kt * 32);
          accx[0] = __builtin_amdgcn_mfma_f32_16x16x32_bf16(a0, w[kt], accx[0], 0, 0, 0);
          accx[1] = __builtin_amdgcn_mfma_f32_16x16x32_bf16(a1, w[kt], accx[1], 0, 0, 0);
        }
      }
    }
  }
}

// ---------------- output projection (outs is slice-layout) ----------------
__launch_bounds__(256, 1)
__global__ void proj_kernel(const short* __restrict__ outs, const short* __restrict__ Woutb,
                            const float* __restrict__ bout, float* __restrict__ logits) {
  const int tid = threadIdx.x, lane = tid & 63, wv = tid >> 6;
  const int l15 = lane & 15, lhi = lane >> 4;
  const int t = blockIdx.x;
  const int row = wv * 16 + l15;
  const short* Abase = outs + (size_t)t * 65536;
  f32x4 acc[8] = {};
  for (int k = 0; k < 1024; k += 32) {
    bf16x8 af = *(const bf16x8*)(Abase + ((k >> 3) + lhi) * 512 + row * 8);
    #pragma unroll
    for (int nn = 0; nn < 8; ++nn) {
      bf16x8 bf = *(const bf16x8*)(Woutb + (size_t)(nn * 16 + l15) * 1024 + k + lhi * 8);
      acc[nn] = __builtin_amdgcn_mfma_f32_16x16x32_bf16(af, bf, acc[nn], 0, 0, 0);
    }
  }
  #pragma unroll
  for (int nn = 0; nn < 8; ++nn) {
    #pragma unroll
    for (int v = 0; v < 4; ++v) {
      int b = wv * 16 + lhi * 4 + v;
      int col = nn * 16 + l15;
      logits[(size_t)b * (cT * cV) + (size_t)t * cV + col] = acc[nn][v] + bout[col];
    }
  }
}

// ---------------- launch ----------------
extern "C" void kernel_launch(void* const* d_in, const int* in_sizes, int n_in,
                              void* d_out, int out_size, void* d_ws, size_t ws_size,
                              hipStream_t stream) {
  const int* x = (const int*)d_in[0];
  const float* embed = (const float*)d_in[1];
  const float* Wx = (const float*)d_in[2];
  const float* Wh = (const float*)d_in[3];
  const float* bias = (const float*)d_in[4];
  const float* Wout = (const float*)d_in[5];
  const float* bout = (const float*)d_in[6];
  float* logits = (float*)d_out;

  char* ws = (char*)d_ws;
  size_t off = 0;
  auto alloc = [&](size_t bytes) {
    char* p = ws + off;
    off += (bytes + 255) & ~(size_t)255;
    return p;
  };
  short* Woutb  = (short*)alloc((size_t)cV * cH * 2);
  short* embedb = (short*)alloc((size_t)cV * cD * 2);
  short* outs   = (short*)alloc((size_t)cT * 65536 * 2);
  short* h0hist = (short*)alloc((size_t)(cT + 1) * 65536 * 2);
  char* state0 = ws + off;
  short* zpage  = (short*)alloc((size_t)65536 * 2);
  int* flags    = (int*)alloc((size_t)NBLK * FSTR * sizeof(int));
  size_t state_bytes = (size_t)((ws + off) - state0);

  hipMemsetAsync(state0, 0, state_bytes, stream);
  hipMemsetAsync(h0hist, 0, (size_t)65536 * 2, stream);   // zero initial-h page

  int n8 = cV * cH / 8;
  cvt_bf16_kernel<<<(n8 + 255) / 256, 256, 0, stream>>>(Wout, Woutb, n8);
  cvt_bf16_kernel<<<(n8 + 255) / 256, 256, 0, stream>>>(embed, embedb, n8);

  RParams P{Wx, Wh, bias, x, embedb, h0hist, outs, zpage, flags};
  lstm_recurrent<<<dim3(NBLK), dim3(512), 0, stream>>>(P);

  proj_kernel<<<cT, 256, 0, stream>>>(outs, Woutb, bout, logits);
}

// Round 14
// 4218.532 us; speedup vs baseline: 5.5364x; 1.0004x over previous
//
#include <hip/hip_runtime.h>
#include <hip/hip_bf16.h>

constexpr int cV = 128, cD = 1024, cH = 1024, cB = 64, cT = 512;
constexpr int c4H = 4096;
constexpr int NBLK = 256;
constexpr int FSTR = 32;            // flag stride in ints (128 B per slot)
// h pages [64][1024] stored slice-wise: [128 oct][64 b][8]; page = 65536 shorts.
// Block (slice,bh) owns rows bh*32..+32, cols 8*slice..+8 -> writes oct=slice, its 32 rows.

typedef __attribute__((ext_vector_type(8))) short bf16x8;
typedef __attribute__((ext_vector_type(4))) float f32x4;
typedef __attribute__((ext_vector_type(4))) int i32x4;

__device__ __forceinline__ short f2b(float f) {
  __hip_bfloat16 h = __float2bfloat16(f);
  return __builtin_bit_cast(short, h);
}
__device__ __forceinline__ float sigf(float x) { return 1.0f / (1.0f + __expf(-x)); }

__device__ __forceinline__ void gload16(const short* g, short* l) {
  __builtin_amdgcn_global_load_lds(
      (const __attribute__((address_space(1))) void*)g,
      (__attribute__((address_space(3))) void*)l, 16, 0, 0);
}

// ---------------- f32 -> bf16 flat converter ----------------
__global__ void cvt_bf16_kernel(const float* __restrict__ src, short* __restrict__ dst, int n8) {
  int q = blockIdx.x * blockDim.x + threadIdx.x;
  if (q >= n8) return;
  const float4* s = (const float4*)src + (size_t)q * 2;
  float4 a = s[0], b = s[1];
  union { short s8[8]; int4 v; } u;
  u.s8[0] = f2b(a.x); u.s8[1] = f2b(a.y); u.s8[2] = f2b(a.z); u.s8[3] = f2b(a.w);
  u.s8[4] = f2b(b.x); u.s8[5] = f2b(b.y); u.s8[6] = f2b(b.z); u.s8[7] = f2b(b.w);
  *(int4*)(dst + (size_t)q * 8) = u.v;
}

// ---------------- fused 2-layer persistent recurrent kernel ----------------
struct RParams {
  const float* Wx;        // [L][4096][1024] f32
  const float* Wh;        // [L][4096][1024] f32
  const float* bias;      // [L][4096]
  const int*   x;         // [B][T]
  const short* embedb;    // [128][1024] bf16
  short* h0hist;          // [T+1] pages; page t+1 = h0(t), page 0 = zeros
  short* outs;            // [T] pages; page t = h1(t)
  const short* zpage;     // zeros page
  int* flags;             // [256*FSTR] per-block arrival words
};

__launch_bounds__(512, 1)
__global__ void lstm_recurrent(RParams P) {
  __shared__ __align__(16) short S0[32768];  // h0(p-1) bh-half: [64 chunk][64 seg][8]
  __shared__ __align__(16) short S1[32768];  // h1(p-2) bh-half
  __shared__ float pLDS[8][32][17];          // per-wave partial [32 batch x 16 cols]
  __shared__ float cLDS[512];                // cell state [layer][32 b][8 hc]
  __shared__ float bLDS[2][32];
  __shared__ short hLDS[512];
  __shared__ int prog[8];                    // monotonic staging progress per wave

  const int tid = threadIdx.x;
  const int lane = tid & 63, wv = tid >> 6;
  const int l15 = lane & 15, lhi = lane >> 4;
  const int op = wv & 3;               // 0=Wx0, 1=Wh0, 2=Wx1, 3=Wh1
  const int ns = wv >> 2;              // col half (16 gate-cols)
  const int blk = blockIdx.x;
  const int slice = blk & 127;
  const int bh = blk >> 7;             // batch half (independent recurrence domain)
  const int hc0 = slice * 8;
  int* F = P.flags;
  const int fbase = bh * 128;

  // ---- one-time: wave's 16x1024 weight slice -> registers ----
  bf16x8 w[32];
  {
    const float* Wsrc = ((op & 1) ? P.Wh : P.Wx) + (size_t)(op >> 1) * c4H * cD;
    int r = ns * 16 + l15;
    const float* base = Wsrc + (size_t)((r >> 3) * cH + hc0 + (r & 7)) * cD + lhi * 8;
    #pragma unroll
    for (int kt = 0; kt < 32; ++kt) {
      float4 a = *(const float4*)(base + kt * 32);
      float4 b = *(const float4*)(base + kt * 32 + 4);
      union { short s8[8]; bf16x8 v; } u;
      u.s8[0] = f2b(a.x); u.s8[1] = f2b(a.y); u.s8[2] = f2b(a.z); u.s8[3] = f2b(a.w);
      u.s8[4] = f2b(b.x); u.s8[5] = f2b(b.y); u.s8[6] = f2b(b.z); u.s8[7] = f2b(b.w);
      w[kt] = u.v;
    }
  }
  if (tid < 64) {
    int l = tid >> 5, r = tid & 31;
    bLDS[l][r] = P.bias[l * c4H + (r >> 3) * cH + hc0 + (r & 7)];
  }
  cLDS[tid] = 0.0f;
  if (tid < 8) prog[tid] = 0;
  __syncthreads();

  for (int p = 0; p <= cT; ++p) {
    const bool l0act = (p < cT);
    const bool l1act = (p >= 1);
    const short* s0g = P.h0hist + (size_t)p * 65536;                     // h0(p-1)
    const short* s1g = (p >= 2) ? (P.outs + (size_t)(p - 2) * 65536) : P.zpage;  // h1(p-2)
    const int p16 = p << 4;

    // ---- per-wave ordered staging: wave owns chunks 8wv..8wv+7 (S0+S1 pair each) ----
    // chunk c covers octs {2c,2c+1}; producers = domain blocks {2c,2c+1}.
    {
      const int* fptr = &F[(fbase + (wv << 4) + (lane & 15)) * FSTR];
      int done = 0;
      while (done < 8) {
        int fv = __hip_atomic_load(fptr, __ATOMIC_RELAXED, __HIP_MEMORY_SCOPE_AGENT);
        unsigned long long bl = __ballot(fv >= p);
        int pr = done;
        while (pr < 8 && ((bl >> (2 * pr)) & 3ull) == 3ull) ++pr;
        if (pr > done) {
          for (int j = done; j < pr; ++j) {
            int oct = (wv << 4) + 2 * j + (lane >> 5);
            int row = lane & 31;
            int seg = (((wv << 3) + j) << 6) + lane;
            gload16(s0g + oct * 512 + bh * 256 + row * 8, S0 + seg * 8);
            gload16(s1g + oct * 512 + bh * 256 + row * 8, S1 + seg * 8);
          }
          asm volatile("s_waitcnt vmcnt(0)" ::: "memory");   // issued chunks landed
          if (lane == 0) ((volatile int*)prog)[wv] = p16 + 2 * pr;
          done = pr;
        } else {
          __builtin_amdgcn_s_sleep(1);
        }
      }
    }

    // ---- GEMM: gated per kt-group on staging progress; op0 ungated (embed) ----
    f32x4 acc[2] = {{0.f,0.f,0.f,0.f}, {0.f,0.f,0.f,0.f}};
    if (op == 0) {
      if (p < cT) {
        int v0 = P.x[(bh * 32 + l15) * cT + p];
        int v1 = P.x[(bh * 32 + 16 + l15) * cT + p];
        const short* e0 = P.embedb + (size_t)v0 * 1024 + lhi * 8;
        const short* e1 = P.embedb + (size_t)v1 * 1024 + lhi * 8;
        #pragma unroll
        for (int kt = 0; kt < 32; ++kt) {
          bf16x8 a0 = *(const bf16x8*)(e0 + kt * 32);
          bf16x8 a1 = *(const bf16x8*)(e1 + kt * 32);
          acc[0] = __builtin_amdgcn_mfma_f32_16x16x32_bf16(a0, w[kt], acc[0], 0, 0, 0);
          acc[1] = __builtin_amdgcn_mfma_f32_16x16x32_bf16(a1, w[kt], acc[1], 0, 0, 0);
        }
      }
    } else {
      const short* S = (op == 3) ? S1 : S0;
      const short* lb = S + lhi * 256 + l15 * 8;
      #pragma unroll
      for (int g = 0; g < 8; ++g) {
        // kt-group g reads chunks 8g..8g+7 == wave g's chunks; full-wave done at p16+16
        while (((volatile int*)prog)[g] < p16 + 16) __builtin_amdgcn_s_sleep(0);
        #pragma unroll
        for (int k4 = 0; k4 < 4; ++k4) {
          constexpr int dummy = 0; (void)dummy;
          int kt = g * 4 + k4;
          bf16x8 a0 = *(const bf16x8*)(lb + kt * 1024);
          bf16x8 a1 = *(const bf16x8*)(lb + kt * 1024 + 128);
          acc[0] = __builtin_amdgcn_mfma_f32_16x16x32_bf16(a0, w[g * 4 + k4], acc[0], 0, 0, 0);
          acc[1] = __builtin_amdgcn_mfma_f32_16x16x32_bf16(a1, w[g * 4 + k4], acc[1], 0, 0, 0);
        }
      }
    }
    #pragma unroll
    for (int mi = 0; mi < 2; ++mi)
      #pragma unroll
      for (int v = 0; v < 4; ++v)
        pLDS[wv][mi * 16 + lhi * 4 + v][l15] = acc[mi][v];
    __syncthreads();   // sync3: all pLDS ready

    // ---- fused x+h reduction + LSTM pointwise (one element per thread) ----
    {
      int l = tid >> 8, b = (tid >> 3) & 31, hc = tid & 7;
      bool act = l ? l1act : l0act;
      if (act) {
        float gt[4];
        #pragma unroll
        for (int g = 0; g < 4; ++g) {
          int r = g * 8 + hc;
          int wB = (r >> 4) * 4 + 2 * l;
          gt[g] = pLDS[wB][b][r & 15] + pLDS[wB + 1][b][r & 15] + bLDS[l][r];
        }
        float cold = cLDS[tid];
        float cn = sigf(gt[1]) * cold + sigf(gt[0]) * tanhf(gt[2]);
        float hn = sigf(gt[3]) * tanhf(cn);
        cLDS[tid] = cn;
        hLDS[tid] = f2b(hn);
      }
    }
    __syncthreads();   // sync4: hLDS complete

    // ---- wave7: writeback + flag (its chunks feed the LAST kt-groups -> self-hiding) ----
    if (wv == 7) {
      bool doStore = (lane < 32) ? l0act : l1act;
      if (doStore) {
        short* d = (lane < 32)
            ? (P.h0hist + (size_t)(p + 1) * 65536 + slice * 512 + bh * 256 + (lane & 31) * 8)
            : (P.outs   + (size_t)(p - 1) * 65536 + slice * 512 + bh * 256 + (lane & 31) * 8);
        i32x4 hv = *(const i32x4*)&hLDS[lane * 8];
        asm volatile("global_store_dwordx4 %0, %1, off sc0 sc1" :: "v"(d), "v"(hv) : "memory");
      }
      asm volatile("s_waitcnt vmcnt(0)" ::: "memory");
      if (lane == 0)
        __hip_atomic_store(&F[blk * FSTR], p + 1, __ATOMIC_RELAXED, __HIP_MEMORY_SCOPE_AGENT);
    }
  }
}

// ---------------- output projection (outs is slice-layout) ----------------
__launch_bounds__(256, 1)
__global__ void proj_kernel(const short* __restrict__ outs, const short* __restrict__ Woutb,
                            const float* __restrict__ bout, float* __restrict__ logits) {
  const int tid = threadIdx.x, lane = tid & 63, wv = tid >> 6;
  const int l15 = lane & 15, lhi = lane >> 4;
  const int t = blockIdx.x;
  const int row = wv * 16 + l15;
  const short* Abase = outs + (size_t)t * 65536;
  f32x4 acc[8] = {};
  for (int k = 0; k < 1024; k += 32) {
    bf16x8 af = *(const bf16x8*)(Abase + ((k >> 3) + lhi) * 512 + row * 8);
    #pragma unroll
    for (int nn = 0; nn < 8; ++nn) {
      bf16x8 bf = *(const bf16x8*)(Woutb + (size_t)(nn * 16 + l15) * 1024 + k + lhi * 8);
      acc[nn] = __builtin_amdgcn_mfma_f32_16x16x32_bf16(af, bf, acc[nn], 0, 0, 0);
    }
  }
  #pragma unroll
  for (int nn = 0; nn < 8; ++nn) {
    #pragma unroll
    for (int v = 0; v < 4; ++v) {
      int b = wv * 16 + lhi * 4 + v;
      int col = nn * 16 + l15;
      logits[(size_t)b * (cT * cV) + (size_t)t * cV + col] = acc[nn][v] + bout[col];
    }
  }
}

// ---------------- launch ----------------
extern "C" void kernel_launch(void* const* d_in, const int* in_sizes, int n_in,
                              void* d_out, int out_size, void* d_ws, size_t ws_size,
                              hipStream_t stream) {
  const int* x = (const int*)d_in[0];
  const float* embed = (const float*)d_in[1];
  const float* Wx = (const float*)d_in[2];
  const float* Wh = (const float*)d_in[3];
  const float* bias = (const float*)d_in[4];
  const float* Wout = (const float*)d_in[5];
  const float* bout = (const float*)d_in[6];
  float* logits = (float*)d_out;

  char* ws = (char*)d_ws;
  size_t off = 0;
  auto alloc = [&](size_t bytes) {
    char* p = ws + off;
    off += (bytes + 255) & ~(size_t)255;
    return p;
  };
  short* Woutb  = (short*)alloc((size_t)cV * cH * 2);
  short* embedb = (short*)alloc((size_t)cV * cD * 2);
  short* outs   = (short*)alloc((size_t)cT * 65536 * 2);
  short* h0hist = (short*)alloc((size_t)(cT + 1) * 65536 * 2);
  char* state0 = ws + off;
  short* zpage  = (short*)alloc((size_t)65536 * 2);
  int* flags    = (int*)alloc((size_t)NBLK * FSTR * sizeof(int));
  size_t state_bytes = (size_t)((ws + off) - state0);

  hipMemsetAsync(state0, 0, state_bytes, stream);
  hipMemsetAsync(h0hist, 0, (size_t)65536 * 2, stream);   // zero initial-h page

  int n8 = cV * cH / 8;
  cvt_bf16_kernel<<<(n8 + 255) / 256, 256, 0, stream>>>(Wout, Woutb, n8);
  cvt_bf16_kernel<<<(n8 + 255) / 256, 256, 0, stream>>>(embed, embedb, n8);

  RParams P{Wx, Wh, bias, x, embedb, h0hist, outs, zpage, flags};
  lstm_recurrent<<<dim3(NBLK), dim3(512), 0, stream>>>(P);

  proj_kernel<<<cT, 256, 0, stream>>>(outs, Woutb, bout, logits);
}